// Round 9
// baseline (502.831 us; speedup 1.0000x reference)
//
#include <hip/hip_runtime.h>
#include <hip/hip_bf16.h>
#include <cmath>
#include <cstring>

#define NNODES 50000
#define NEDGES 800000
#define IND    512
#define HD     128
#define CD     64

typedef __bf16 bf16x8 __attribute__((ext_vector_type(8)));
typedef float  f32x4  __attribute__((ext_vector_type(4)));
typedef const __attribute__((address_space(1))) unsigned int* gu32p;
typedef __attribute__((address_space(3))) unsigned int* lu32p;

// ---------------- workspace layout (byte offsets) ----------------
static const size_t XJ_B   = 0;           // bf16 50000x256 (agg output; x_bf16 overlay early)
static const size_t HID_B  = 25600000;    // dead region; ew partial sums overlay (post-G1)
static const size_t H1_B   = 51200000;    // bf16 50000x512
static const size_t XW_B   = 102400000;   // bf16 50000x128
static const size_t CNT8_B = 115200000;   // int 8x50000 per-XCD degree counters (dead H2 area)
static const size_t LG_B   = 121600000;   // bf16 50000x64
static const size_t PE_B   = 128000000;   // bf16 50000x64
static const size_t WT_B   = 134400000;   // transposed bf16 weights + biases (~0.9MB)
static const size_t CSRR_B = 135300000;   // int 800000 (csr row index)
static const size_t EWC_B  = 138500000;   // fp32 800000 (ew in CSR order; normalized in place)
static const size_t CSRW_B = 141700000;   // int csr_col -> then fp32 csr_w (overlay)
static const size_t CNT_B  = 144900000;   // int 50000 (merged counts, written by scan1)
static const size_t S_B    = 145100000;   // 2 doubles (zeroed)
static const size_t RP_B   = 145100016;   // int 50001
static const size_t WOFF_B = 145300020;   // int 50000
static const size_t INCL_B = 145500020;   // int 50000
static const size_t BSUM_B = 145700020;   // int 256
static const size_t DIS_B  = 145701052;   // fp32 50000
// x_bf16 overlay: [XJ_B, XJ_B+51.2MB) = xj+hid regions; dead before their real
// writers run. GEMM A-tile over-reads (<=48 rows) land in the next ws region.
// ew partials: 25000 x 2 doubles (400KB) at HID_B -- region dead after G1.
// cnt8: round-8 lesson -- 800k device atomics bouncing one 200KB table across
// 8 non-coherent XCD L2s cost ~40us + ~24MB HBM writes; per-XCD replicas
// (blockIdx&7 = default XCD round-robin) keep each copy L2-local.

// weight sub-offsets (bytes within WT_B). Wp1t then Wg0t CONTIGUOUS (G1 fused
// Bt [640,512]); Wp3t then W2t=(Wp3@P)t CONTIGUOUS (G2G3 stage-2 Bt [128,64]).
static const size_t WP1T_O = 0;       // 512x512
static const size_t WG0T_O = 524288;  // 128x512
static const size_t WP2T_O = 655360;  // 64x512
static const size_t WP3T_O = 720896;  // 64x64
static const size_t W2T_O  = 729088;  // 64x64 (Wp3 @ relu(2*P0), transposed)
static const size_t WG1T_O = 737280;  // 128x128
static const size_t WL1T_O = 770048;  // 128x256
static const size_t WL2T_O = 835584;  // 64x128
static const size_t BG1_O  = 851968;  // fp32 640: [bp1 | zeros(128)]
static const size_t BG3_O  = 854528;  // fp32 128: [bp3 | bp3@P]

// ---------------- fused prep: x cast + weight transposes + P0 fold + count -
struct WD { const float* s; __hip_bfloat16* d; int K; int N; };
struct PrepArgs {
    const float* x; __hip_bfloat16* xb;
    WD w[7];
    int bo[8];                       // cumulative TILE offsets per matrix
    const float* Wp3; const float* bp3; const float* P0; const float* bp1;
    __hip_bfloat16* W2t; float* bias_g1; float* bias_g3;
    const int* ei; int* cnt8;        // per-XCD degree counters
};
#define PREP_CAST_BLKS  12500
#define PREP_TP_BLKS    103
#define PREP_CMB_BLKS   20
#define PREP_CNT_BLKS   3125
#define PREP_BLKS (PREP_CAST_BLKS + PREP_TP_BLKS + PREP_CMB_BLKS + PREP_CNT_BLKS)

__global__ __launch_bounds__(256) void prep_all(PrepArgs a)
{
    __shared__ __hip_bfloat16 tile[64][65];
    int b = blockIdx.x;
    int t = threadIdx.x;
    if (b < PREP_CAST_BLKS) {                 // ---- x fp32 -> bf16 (exact) ----
        int i = b * 256 + t;                  // 12500*256 == 50000*512/8 exactly
        const float4* p = (const float4*)a.x + (size_t)i * 2;
        float4 u = p[0], v = p[1];
        __hip_bfloat16 o[8] __attribute__((aligned(16)));
        o[0] = __float2bfloat16(u.x); o[1] = __float2bfloat16(u.y);
        o[2] = __float2bfloat16(u.z); o[3] = __float2bfloat16(u.w);
        o[4] = __float2bfloat16(v.x); o[5] = __float2bfloat16(v.y);
        o[6] = __float2bfloat16(v.z); o[7] = __float2bfloat16(v.w);
        *(int4*)(a.xb + (size_t)i * 8) = *(const int4*)o;
        return;
    }
    b -= PREP_CAST_BLKS;
    if (b < PREP_TP_BLKS) {                   // ---- LDS-tiled transpose+cast ----
        int m = 0;
        #pragma unroll
        for (int q = 1; q < 7; q++) if (b >= a.bo[q]) m = q;
        WD d = a.w[m];
        int q = b - a.bo[m];
        int ntn = d.N >> 6;                   // tiles across n
        int tk = (q / ntn) << 6;
        int tn = (q % ntn) << 6;
        int rr = t >> 6, cc = t & 63;
        #pragma unroll
        for (int r8 = 0; r8 < 16; r8++) {     // read: coalesced over n
            int row = r8 * 4 + rr;            // k within tile
            tile[row][cc] = __float2bfloat16(d.s[(size_t)(tk + row) * d.N + tn + cc]);
        }
        __syncthreads();
        #pragma unroll
        for (int r8 = 0; r8 < 16; r8++) {     // write: coalesced over k
            int n = r8 * 4 + rr;              // n within tile
            d.d[(size_t)(tn + n) * d.K + tk + cc] = tile[cc][n];
        }
        return;
    }
    b -= PREP_TP_BLKS;
    if (b < PREP_CMB_BLKS) {                  // ---- combine_p0 (20 blocks) ----
        if (b < 16) {
            int i = b * 256 + t;
            int k = i >> 6, n = i & 63;
            float s = 0.f;
            for (int j = 0; j < 64; j++)
                s += a.Wp3[k * 64 + j] * fmaxf(2.f * a.P0[j * 64 + n], 0.f);
            a.W2t[n * 64 + k] = __float2bfloat16(s);
        } else if (b == 16) {
            int n = t;
            if (n < 64) {
                float s = 0.f;
                for (int j = 0; j < 64; j++)
                    s += a.bp3[j] * fmaxf(2.f * a.P0[j * 64 + n], 0.f);
                a.bias_g3[n] = a.bp3[n];
                a.bias_g3[64 + n] = s;
            }
        } else {
            int i = (b - 17) * 256 + t;       // 0..767
            if (i < 512) a.bias_g1[i] = a.bp1[i];
            else if (i < 640) a.bias_g1[i] = 0.f;
        }
        return;
    }
    b -= PREP_CMB_BLKS;                       // ---- degree count (3125 blocks) ----
    int e = b * 256 + t;                      // 3125*256 == 800000 exactly
    int xcd = blockIdx.x & 7;                 // default round-robin block->XCD map
    atomicAdd(&a.cnt8[xcd * NNODES + a.ei[NEDGES + e]], 1);
}

// ---------------- bf16 MFMA GEMM: C = act(A[M,K] @ Bt[N,K]^T + bias) -------
// 4 waves, wave tile (BM/2) x WN, BN = 2*WN. K%64==0, N%BN==0.
// BK=64 via TWIN 32-wide tiles: both half-tiles' global_load_lds issued
// back-to-back (2x MLP per drain), ONE barrier, then MFMAs. Trailing barrier
// skipped on last K-step. Explicit dbuf REGRESSED (round 2); WN=32 for G1
// REGRESSED (round 7). BM=64 kept for small-N GEMMs.
template<int BM, int BN, int WN>
__global__ __launch_bounds__(256) void gemm_mfma(
    const __hip_bfloat16* __restrict__ Ab, int lda,
    const __hip_bfloat16* __restrict__ Bt, int ldb,
    const float* __restrict__ bias,
    void* __restrict__ Cout, int ldc,
    void* __restrict__ Cout2, int ldc2, int splitN,
    int M, int K, int do_relu, int out_bf16)
{
    constexpr int BF = WN / 16;       // col frags per wave
    constexpr int MI = BM / 32;       // row frags per wave
    constexpr int APASS = BM / 64;    // A staging passes per 32-wide tile
    constexpr int BPASS = BN / 64;    // B staging passes per 32-wide tile
    __shared__ __bf16 As[2][BM * 32];
    __shared__ __bf16 Bs[2][BN * 32];

    const int NC = gridDim.x, NR = gridDim.y;
    int g = blockIdx.y * NC + blockIdx.x;
    int per = NC * 8;
    int nfull = (NR >> 3) * per;
    int rowt, colt;
    if (g < nfull) {
        int grp = g / per, rem = g % per;
        rowt = grp * 8 + (rem & 7);
        colt = rem >> 3;
    } else {
        int rem = g - nfull;
        int tail = NR - (NR >> 3) * 8;
        rowt = (NR >> 3) * 8 + rem % tail;
        colt = rem / tail;
    }

    const int t = threadIdx.x;
    const int row0 = rowt * BM;
    const int col0 = colt * BN;

    const int wv   = t >> 6;
    const int lane = t & 63;
    const int quad = lane >> 4;
    const int l16  = lane & 15;
    const int wrow = (wv >> 1) * (BM / 2);
    const int wcol = (wv & 1) * WN;

    const int subrow = lane >> 2;                          // 0..15
    const int kchunk = (lane & 3) ^ (subrow & 3);          // swizzled chunk
    const int subkg  = kchunk * 8;

    f32x4 acc[MI][BF] = {};

    for (int k0 = 0; k0 < K; k0 += 64) {
        #pragma unroll
        for (int h = 0; h < 2; h++) {
            int kh = k0 + h * 32;
            #pragma unroll
            for (int p = 0; p < APASS; p++) {
                int rowA = (p * 4 + wv) * 16 + subrow;
                const __hip_bfloat16* gp = Ab + (size_t)(row0 + rowA) * lda + kh + subkg;
                __builtin_amdgcn_global_load_lds((gu32p)(const void*)gp,
                    (lu32p)(void*)&As[h][(p * 4 + wv) * 512], 16, 0, 0);
            }
            #pragma unroll
            for (int p = 0; p < BPASS; p++) {
                int rowB = (p * 4 + wv) * 16 + subrow;
                const __hip_bfloat16* gp = Bt + (size_t)(col0 + rowB) * ldb + kh + subkg;
                __builtin_amdgcn_global_load_lds((gu32p)(const void*)gp,
                    (lu32p)(void*)&Bs[h][(p * 4 + wv) * 512], 16, 0, 0);
            }
        }
        __syncthreads();

        #pragma unroll
        for (int h = 0; h < 2; h++) {
            bf16x8 af[MI], bfr[BF];
            #pragma unroll
            for (int i = 0; i < MI; i++) {
                int R = wrow + i * 16 + l16;
                af[i] = *(const bf16x8*)&As[h][R * 32 + ((quad ^ (R & 3)) * 8)];
            }
            #pragma unroll
            for (int j = 0; j < BF; j++) {
                int R = wcol + j * 16 + l16;
                bfr[j] = *(const bf16x8*)&Bs[h][R * 32 + ((quad ^ (R & 3)) * 8)];
            }
            #pragma unroll
            for (int i = 0; i < MI; i++)
                #pragma unroll
                for (int j = 0; j < BF; j++)
                    acc[i][j] = __builtin_amdgcn_mfma_f32_16x16x32_bf16(af[i], bfr[j], acc[i][j], 0, 0, 0);
        }
        if (k0 + 64 < K) __syncthreads();
    }

    #pragma unroll
    for (int i = 0; i < MI; i++) {
        #pragma unroll
        for (int j = 0; j < BF; j++) {
            int n = col0 + wcol + j * 16 + l16;
            bool second = (n >= splitN);
            float bv = bias ? bias[n] : 0.f;
            #pragma unroll
            for (int reg = 0; reg < 4; reg++) {
                int m = row0 + wrow + i * 16 + quad * 4 + reg;
                if (m >= M) continue;
                float v = acc[i][j][reg] + bv;
                if (do_relu && !second) v = fmaxf(v, 0.f);
                if (second)
                    ((__hip_bfloat16*)Cout2)[(size_t)m * ldc2 + (n - splitN)] = __float2bfloat16(v);
                else if (out_bf16)
                    ((__hip_bfloat16*)Cout)[(size_t)m * ldc + n] = __float2bfloat16(v);
                else
                    ((float*)Cout)[(size_t)m * ldc + n] = v;
            }
        }
    }
}

// ---------------- fused 2-stage GEMM ---------------------------------------
// Stage 1: T[64,BN1] = relu(A[M,K1] @ B1t[BN1,K1]^T + bias1) held in LDS.
// Stage 2: Out[64,N2] = T @ B2t[N2,BN1]^T + bias2.  (see round-4 notes)
template<int BN1, int WN1, int N2, int SPLIT2, int OUT2F32>
__global__ __launch_bounds__(256) void gemm_fused(
    const __hip_bfloat16* __restrict__ Ab, int lda,
    const __hip_bfloat16* __restrict__ B1t, int ldb1,
    const float* __restrict__ bias1,
    const __hip_bfloat16* __restrict__ B2t,
    const float* __restrict__ bias2,
    void* __restrict__ Out1, int ldo1,
    void* __restrict__ Out2, int ldo2,
    int M, int K1)
{
    constexpr int BF1 = WN1 / 16;
    constexpr int BPASS1 = BN1 / 64;
    constexpr int K2H = BN1 / 32;        // stage-2 K chunks of 32
    constexpr int WN2 = N2 / 2;
    constexpr int BF2 = WN2 / 16;
    constexpr int P2 = N2 / 64;
    __shared__ __bf16 L1[4096 + BN1 * 64];   // [As(2x2048) | Bs1(2 x BN1*32)]
    __shared__ __bf16 Bs2[8192];             // K2H x N2*32 (= BN1*N2 = 8192 both cfgs)

    const int t = threadIdx.x;
    const int row0 = blockIdx.y * 64;
    const int wv   = t >> 6;
    const int lane = t & 63;
    const int quad = lane >> 4;
    const int l16  = lane & 15;
    const int wrow1 = (wv >> 1) * 32;
    const int wcol1 = (wv & 1) * WN1;
    const int subrow = lane >> 2;
    const int subkg  = ((lane & 3) ^ (subrow & 3)) * 8;

    // stage B2 once (drains with first K-loop barrier)
    #pragma unroll
    for (int hh = 0; hh < K2H; hh++)
        #pragma unroll
        for (int p = 0; p < P2; p++) {
            int rowB = (p * 4 + wv) * 16 + subrow;
            const __hip_bfloat16* gp = B2t + (size_t)rowB * BN1 + hh * 32 + subkg;
            __builtin_amdgcn_global_load_lds((gu32p)(const void*)gp,
                (lu32p)(void*)&Bs2[hh * (N2 * 32) + (p * 4 + wv) * 512], 16, 0, 0);
        }

    f32x4 acc1[2][BF1] = {};
    for (int k0 = 0; k0 < K1; k0 += 64) {
        #pragma unroll
        for (int h = 0; h < 2; h++) {
            int kh = k0 + h * 32;
            {
                int rowA = wv * 16 + subrow;
                const __hip_bfloat16* gp = Ab + (size_t)(row0 + rowA) * lda + kh + subkg;
                __builtin_amdgcn_global_load_lds((gu32p)(const void*)gp,
                    (lu32p)(void*)&L1[h * 2048 + wv * 512], 16, 0, 0);
            }
            #pragma unroll
            for (int p = 0; p < BPASS1; p++) {
                int rowB = (p * 4 + wv) * 16 + subrow;
                const __hip_bfloat16* gp = B1t + (size_t)rowB * ldb1 + kh + subkg;
                __builtin_amdgcn_global_load_lds((gu32p)(const void*)gp,
                    (lu32p)(void*)&L1[4096 + h * (BN1 * 32) + (p * 4 + wv) * 512], 16, 0, 0);
            }
        }
        __syncthreads();
        #pragma unroll
        for (int h = 0; h < 2; h++) {
            bf16x8 af[2], bfr[BF1];
            #pragma unroll
            for (int i = 0; i < 2; i++) {
                int R = wrow1 + i * 16 + l16;
                af[i] = *(const bf16x8*)&L1[h * 2048 + R * 32 + ((quad ^ (R & 3)) * 8)];
            }
            #pragma unroll
            for (int j = 0; j < BF1; j++) {
                int R = wcol1 + j * 16 + l16;
                bfr[j] = *(const bf16x8*)&L1[4096 + h * (BN1 * 32) + R * 32 + ((quad ^ (R & 3)) * 8)];
            }
            #pragma unroll
            for (int i = 0; i < 2; i++)
                #pragma unroll
                for (int j = 0; j < BF1; j++)
                    acc1[i][j] = __builtin_amdgcn_mfma_f32_16x16x32_bf16(af[i], bfr[j], acc1[i][j], 0, 0, 0);
        }
        __syncthreads();   // ALWAYS: T overlays As/Bs next (or next stage)
    }

    // T = relu(acc1 + bias1) -> bf16 into L1 (swizzled layout, overlay)
    #pragma unroll
    for (int i = 0; i < 2; i++)
        #pragma unroll
        for (int j = 0; j < BF1; j++) {
            int n1 = wcol1 + j * 16 + l16;
            float bv = bias1[n1];
            int h = n1 >> 5, kk = n1 & 31;
            int q = kk >> 3, pp = kk & 7;
            #pragma unroll
            for (int reg = 0; reg < 4; reg++) {
                int r = wrow1 + i * 16 + quad * 4 + reg;
                float v = fmaxf(acc1[i][j][reg] + bv, 0.f);
                __hip_bfloat16 hb = __float2bfloat16(v);
                unsigned short us; memcpy(&us, &hb, 2);
                *(unsigned short*)&L1[h * 2048 + r * 32 + ((q ^ (r & 3)) * 8) + pp] = us;
            }
        }
    __syncthreads();

    // stage 2
    const int wrow2 = (wv >> 1) * 32;
    const int wcol2 = (wv & 1) * WN2;
    f32x4 acc2[2][BF2] = {};
    #pragma unroll
    for (int hh = 0; hh < K2H; hh++) {
        bf16x8 af2[2], bf2[BF2];
        #pragma unroll
        for (int i = 0; i < 2; i++) {
            int R = wrow2 + i * 16 + l16;
            af2[i] = *(const bf16x8*)&L1[hh * 2048 + R * 32 + ((quad ^ (R & 3)) * 8)];
        }
        #pragma unroll
        for (int j = 0; j < BF2; j++) {
            int R = wcol2 + j * 16 + l16;
            bf2[j] = *(const bf16x8*)&Bs2[hh * (N2 * 32) + R * 32 + ((quad ^ (R & 3)) * 8)];
        }
        #pragma unroll
        for (int i = 0; i < 2; i++)
            #pragma unroll
            for (int j = 0; j < BF2; j++)
                acc2[i][j] = __builtin_amdgcn_mfma_f32_16x16x32_bf16(af2[i], bf2[j], acc2[i][j], 0, 0, 0);
    }

    #pragma unroll
    for (int i = 0; i < 2; i++)
        #pragma unroll
        for (int j = 0; j < BF2; j++) {
            int n2 = wcol2 + j * 16 + l16;
            float bv = bias2[n2];
            #pragma unroll
            for (int reg = 0; reg < 4; reg++) {
                int m = row0 + wrow2 + i * 16 + quad * 4 + reg;
                if (m >= M) continue;
                float v = acc2[i][j][reg] + bv;
                if (SPLIT2) {
                    if (n2 < 64)
                        ((__hip_bfloat16*)Out1)[(size_t)m * ldo1 + n2] = __float2bfloat16(v);
                    else
                        ((__hip_bfloat16*)Out2)[(size_t)m * ldo2 + (n2 - 64)] = __float2bfloat16(v);
                } else if (OUT2F32) {
                    ((float*)Out1)[(size_t)m * ldo1 + n2] = v;
                } else {
                    ((__hip_bfloat16*)Out1)[(size_t)m * ldo1 + n2] = __float2bfloat16(v);
                }
            }
        }
}

// ---------------- CSR build (count fused into prep_all, per-XCD) -----------
// scan1 merges the 8 per-XCD count replicas (coalesced 1.6MB read), stores
// the merged count into cnt[] for scan3, then scans as before.
__global__ __launch_bounds__(256) void scan1_kernel(
    const int* __restrict__ cnt8, int* __restrict__ cnt,
    int* __restrict__ incl, int* __restrict__ bsum)
{
    __shared__ int s[256];
    int t = threadIdx.x;
    int i = blockIdx.x * 256 + t;
    int v = 0;
    if (i < NNODES) {
        #pragma unroll
        for (int x = 0; x < 8; x++) v += cnt8[x * NNODES + i];
        cnt[i] = v;
    }
    s[t] = v;
    __syncthreads();
    for (int off = 1; off < 256; off <<= 1) {
        int u = (t >= off) ? s[t - off] : 0;
        __syncthreads();
        s[t] += u;
        __syncthreads();
    }
    if (i < NNODES) incl[i] = s[t];
    if (t == 255) bsum[blockIdx.x] = s[255];
}

// scan3 with scan2 folded in: every block redundantly scans the 196 block
// sums in LDS (identical integer math to the old scan2+scan3 pair).
__global__ __launch_bounds__(256) void scan3_kernel(
    const int* __restrict__ cnt, const int* __restrict__ incl,
    const int* __restrict__ bsum, int* __restrict__ rowptr,
    int* __restrict__ woff, int nb)
{
    __shared__ int s[256];
    int t = threadIdx.x;
    int v = (t < nb) ? bsum[t] : 0;
    s[t] = v;
    __syncthreads();
    for (int off = 1; off < 256; off <<= 1) {
        int u = (t >= off) ? s[t - off] : 0;
        __syncthreads();
        s[t] += u;
        __syncthreads();
    }
    int off = s[blockIdx.x] - bsum[blockIdx.x];   // exclusive prefix of own block
    int i = blockIdx.x * 256 + t;
    if (i >= NNODES) return;
    int r = incl[i] - cnt[i] + off;
    rowptr[i] = r;
    woff[i] = r;
    if (i == NNODES - 1) rowptr[NNODES] = incl[i] + off;
}

__global__ __launch_bounds__(256) void scatter_idx_kernel(
    const int* __restrict__ ei, int* __restrict__ woff,
    int* __restrict__ csr_row, int* __restrict__ csr_col)
{
    int e = blockIdx.x * 256 + threadIdx.x;
    if (e >= NEDGES) return;
    int r = ei[e];
    int c = ei[NEDGES + e];
    int p = atomicAdd(&woff[c], 1);
    csr_row[p] = r;
    csr_col[p] = c;
}

// ---------------- edge weight: 8 lanes per edge; partial sums NO atomics ---
// Round-6 lesson: 50000 same-address double atomicAdds serialized (~600us);
// per-block partials (plain stores) + tiny reduce instead.
__global__ __launch_bounds__(256) void edge_ew_gather(
    const __hip_bfloat16* __restrict__ lg, const __hip_bfloat16* __restrict__ pe,
    const int* __restrict__ csr_row, const int* __restrict__ csr_col,
    float* __restrict__ ew_csr, double* __restrict__ part)
{
    const int tid = threadIdx.x;
    const int sub = tid & 7;
    const int e = blockIdx.x * 32 + (tid >> 3);   // 25000*32 == 800000 exactly
    int r = csr_row[e];
    int c = csr_col[e];
    bf16x8 a = *(const bf16x8*)(lg + (size_t)r * CD + sub * 8);
    bf16x8 b = *(const bf16x8*)(pe + (size_t)c * CD + sub * 8);
    float acc = 0.f;
    #pragma unroll
    for (int u = 0; u < 8; u++)
        acc += (float)a[u] * (float)b[u];
    acc += __shfl_xor(acc, 1);
    acc += __shfl_xor(acc, 2);
    acc += __shfl_xor(acc, 4);
    if (sub == 0) ew_csr[e] = acc;

    double s1 = (sub == 0) ? (double)acc : 0.0;
    double s2 = (sub == 0) ? (double)acc * (double)acc : 0.0;
    #pragma unroll
    for (int off = 8; off < 64; off <<= 1) {      // combine the 8 sub0 lanes/wave
        s1 += __shfl_xor(s1, off);
        s2 += __shfl_xor(s2, off);
    }
    __shared__ double sh1[4], sh2[4];
    if ((tid & 63) == 0) { sh1[tid >> 6] = s1; sh2[tid >> 6] = s2; }
    __syncthreads();
    if (tid == 0) {
        part[2 * blockIdx.x]     = sh1[0] + sh1[1] + sh1[2] + sh1[3];
        part[2 * blockIdx.x + 1] = sh2[0] + sh2[1] + sh2[2] + sh2[3];
    }
}

// reduce the 25000 partial pairs into S (64 total atomics -- no contention)
__global__ __launch_bounds__(256) void ew_reduce_kernel(
    const double* __restrict__ part, double* __restrict__ S)
{
    const int tid = threadIdx.x;
    double s1 = 0.0, s2 = 0.0;
    for (int i = blockIdx.x * 256 + tid; i < 25000; i += gridDim.x * 256) {
        s1 += part[2 * i];
        s2 += part[2 * i + 1];
    }
    __shared__ double sh1[256], sh2[256];
    sh1[tid] = s1; sh2[tid] = s2;
    __syncthreads();
    for (int s = 128; s > 0; s >>= 1) {
        if (tid < s) { sh1[tid] += sh1[tid + s]; sh2[tid] += sh2[tid + s]; }
        __syncthreads();
    }
    if (tid == 0) {
        atomicAdd(&S[0], sh1[0]);
        atomicAdd(&S[1], sh2[0]);
    }
}

// per node: normalize segment in place, deg = segment sum, dis = rsqrt(deg+1).
__global__ __launch_bounds__(256) void norm_deg_kernel(
    const int* __restrict__ rowptr, float* __restrict__ ew_csr,
    const double* __restrict__ S, float* __restrict__ dis)
{
    int n = blockIdx.x * 256 + threadIdx.x;
    if (n >= NNODES) return;
    const double Ed = (double)NEDGES;
    double meand = S[0] / Ed;
    double var = (S[1] - S[0] * S[0] / Ed) / (Ed - 1.0);
    float mean = (float)meand;
    float alpha = (float)sqrt(1e-4 / var);
    int s = rowptr[n], e = rowptr[n + 1];
    float sum = 0.f;
    for (int j = s; j < e; j++) {
        float w = (ew_csr[j] - mean) * alpha + 1.0f;
        ew_csr[j] = w;
        sum += w;
    }
    float d = sum + 1.0f;                       // self-loop weight 1
    dis[n] = (d > 0.f) ? rsqrtf(d) : 0.f;
}

// per node: csr_w[j] = dis[row]*w*dis[n]  (csr_w overlays the dead csr_col)
__global__ __launch_bounds__(256) void csrw_kernel(
    const int* __restrict__ rowptr, const int* __restrict__ csr_row,
    const float* __restrict__ ew_csr, const float* __restrict__ dis,
    float* __restrict__ csr_w)
{
    int n = blockIdx.x * 256 + threadIdx.x;
    if (n >= NNODES) return;
    float dn = dis[n];
    int s = rowptr[n], e = rowptr[n + 1];
    for (int j = s; j < e; j++)
        csr_w[j] = dis[csr_row[j]] * ew_csr[j] * dn;
}

// ---------------- weighted aggregation, MLP-optimized ----------------------
__global__ __launch_bounds__(128) void agg_kernel(
    const unsigned* __restrict__ xw32, const float* __restrict__ dis,
    const int* __restrict__ rowptr, const int* __restrict__ csr_row,
    const float* __restrict__ csr_w, const float* __restrict__ bias,
    __hip_bfloat16* __restrict__ out, int ldo)
{
    const int wv = threadIdx.x >> 6, lane = threadIdx.x & 63;
    const int n = blockIdx.x * 2 + wv;
    if (n >= NNODES) return;
    float dn = dis[n];
    unsigned v0 = xw32[(size_t)n * 64 + lane];
    float aL = dn * dn * __uint_as_float(v0 << 16);
    float aH = dn * dn * __uint_as_float(v0 & 0xffff0000u);
    int s = rowptr[n], e = rowptr[n + 1];
    int j = s;
    for (; j + 4 <= e; j += 4) {
        int r0 = csr_row[j], r1 = csr_row[j + 1];
        int r2 = csr_row[j + 2], r3 = csr_row[j + 3];
        float w0 = csr_w[j], w1 = csr_w[j + 1];
        float w2 = csr_w[j + 2], w3 = csr_w[j + 3];
        unsigned g0 = xw32[(size_t)r0 * 64 + lane];
        unsigned g1 = xw32[(size_t)r1 * 64 + lane];
        unsigned g2 = xw32[(size_t)r2 * 64 + lane];
        unsigned g3 = xw32[(size_t)r3 * 64 + lane];
        aL = fmaf(w0, __uint_as_float(g0 << 16), aL);
        aH = fmaf(w0, __uint_as_float(g0 & 0xffff0000u), aH);
        aL = fmaf(w1, __uint_as_float(g1 << 16), aL);
        aH = fmaf(w1, __uint_as_float(g1 & 0xffff0000u), aH);
        aL = fmaf(w2, __uint_as_float(g2 << 16), aL);
        aH = fmaf(w2, __uint_as_float(g2 & 0xffff0000u), aH);
        aL = fmaf(w3, __uint_as_float(g3 << 16), aL);
        aH = fmaf(w3, __uint_as_float(g3 & 0xffff0000u), aH);
    }
    for (; j < e; j++) {
        int r = csr_row[j];
        float w = csr_w[j];
        unsigned g = xw32[(size_t)r * 64 + lane];
        aL = fmaf(w, __uint_as_float(g << 16), aL);
        aH = fmaf(w, __uint_as_float(g & 0xffff0000u), aH);
    }
    float2 b = *(const float2*)(bias + 2 * lane);
    aL = fmaxf(aL + b.x, 0.f);
    aH = fmaxf(aH + b.y, 0.f);
    __hip_bfloat16 bl = __float2bfloat16(aL), bh = __float2bfloat16(aH);
    unsigned short ul, uh;
    memcpy(&ul, &bl, 2); memcpy(&uh, &bh, 2);
    unsigned o = (unsigned)ul | ((unsigned)uh << 16);
    *(unsigned*)(out + (size_t)n * ldo + 2 * lane) = o;
}

// ---------------- launch --------------------------------------------------
extern "C" void kernel_launch(void* const* d_in, const int* in_sizes, int n_in,
                              void* d_out, int out_size, void* d_ws, size_t ws_size,
                              hipStream_t stream)
{
    const float* x   = (const float*)d_in[0];
    const int*   ei  = (const int*)d_in[1];
    const float* Wp1 = (const float*)d_in[2];
    const float* bp1 = (const float*)d_in[3];
    const float* Wp2 = (const float*)d_in[4];
    const float* bp2 = (const float*)d_in[5];
    const float* Wp3 = (const float*)d_in[6];
    const float* bp3 = (const float*)d_in[7];
    const float* P0  = (const float*)d_in[8];
    const float* Wg0 = (const float*)d_in[9];
    const float* bg0 = (const float*)d_in[10];
    const float* Wg1 = (const float*)d_in[11];
    const float* bg1 = (const float*)d_in[12];
    // d_in[13], d_in[14] = Wg2/bg2: dead in reference
    const float* Wl1 = (const float*)d_in[15];
    const float* bl1 = (const float*)d_in[16];
    const float* Wl2 = (const float*)d_in[17];
    const float* bl2 = (const float*)d_in[18];
    float* out = (float*)d_out;

    char* wsb = (char*)d_ws;
    __hip_bfloat16* xj     = (__hip_bfloat16*)(wsb + XJ_B);
    __hip_bfloat16* xb16   = (__hip_bfloat16*)(wsb + XJ_B);  // x bf16 overlay (early)
    double*         part   = (double*)(wsb + HID_B);         // ew partials (post-G1)
    __hip_bfloat16* h1     = (__hip_bfloat16*)(wsb + H1_B);
    __hip_bfloat16* xw     = (__hip_bfloat16*)(wsb + XW_B);
    int*            cnt8   = (int*)(wsb + CNT8_B);           // per-XCD degree counters
    __hip_bfloat16* lg     = (__hip_bfloat16*)(wsb + LG_B);
    __hip_bfloat16* pe     = (__hip_bfloat16*)(wsb + PE_B);
    int*            csr_row= (int*)(wsb + CSRR_B);
    float*          ew_csr = (float*)(wsb + EWC_B);
    int*            csr_col= (int*)(wsb + CSRW_B);   // overlays csr_w (dead until csrw_kernel)
    float*          csr_w  = (float*)(wsb + CSRW_B);
    int*            cnt    = (int*)(wsb + CNT_B);
    double*         S      = (double*)(wsb + S_B);
    int*            rowptr = (int*)(wsb + RP_B);
    int*            woff   = (int*)(wsb + WOFF_B);
    int*            incl   = (int*)(wsb + INCL_B);
    int*            bsum   = (int*)(wsb + BSUM_B);
    float*          dis    = (float*)(wsb + DIS_B);

    __hip_bfloat16* Wp1t = (__hip_bfloat16*)(wsb + WT_B + WP1T_O);
    __hip_bfloat16* Wg0t = (__hip_bfloat16*)(wsb + WT_B + WG0T_O);
    __hip_bfloat16* Wp2t = (__hip_bfloat16*)(wsb + WT_B + WP2T_O);
    __hip_bfloat16* Wp3t = (__hip_bfloat16*)(wsb + WT_B + WP3T_O);
    __hip_bfloat16* W2t  = (__hip_bfloat16*)(wsb + WT_B + W2T_O);
    __hip_bfloat16* Wg1t = (__hip_bfloat16*)(wsb + WT_B + WG1T_O);
    __hip_bfloat16* Wl1t = (__hip_bfloat16*)(wsb + WT_B + WL1T_O);
    __hip_bfloat16* Wl2t = (__hip_bfloat16*)(wsb + WT_B + WL2T_O);
    float*          bias_g1 = (float*)(wsb + WT_B + BG1_O);
    float*          bias_g3 = (float*)(wsb + WT_B + BG3_O);

    const int EB = (NEDGES + 255) / 256;            // 3125
    const int NB = (NNODES + 255) / 256;            // 196
    const int MT  = (NNODES + 127) / 128;           // 391 row tiles (BM=128)
    const int MT64 = (NNODES + 63) / 64;            // 782 row tiles (BM=64)
    const int BIGN = 1 << 30;

    hipMemsetAsync(wsb + CNT8_B, 0, 8 * NNODES * sizeof(int), stream);
    hipMemsetAsync(wsb + S_B, 0, 16, stream);

    // --- fused prep: x cast + tiled weight transposes + P0 fold + count ---
    PrepArgs pa;
    pa.x = x; pa.xb = xb16;
    pa.w[0] = { Wp1, Wp1t, 512, 512 };
    pa.w[1] = { Wg0, Wg0t, 512, 128 };
    pa.w[2] = { Wp2, Wp2t, 512,  64 };
    pa.w[3] = { Wp3, Wp3t,  64,  64 };
    pa.w[4] = { Wg1, Wg1t, 128, 128 };
    pa.w[5] = { Wl1, Wl1t, 256, 128 };
    pa.w[6] = { Wl2, Wl2t, 128,  64 };
    // 64x64 tiles per matrix: 64,16,8,1,4,8,2 (cumulative below)
    pa.bo[0] = 0;  pa.bo[1] = 64; pa.bo[2] = 80; pa.bo[3] = 88;
    pa.bo[4] = 89; pa.bo[5] = 93; pa.bo[6] = 101; pa.bo[7] = 103;
    pa.Wp3 = Wp3; pa.bp3 = bp3; pa.P0 = P0; pa.bp1 = bp1;
    pa.W2t = W2t; pa.bias_g1 = bias_g1; pa.bias_g3 = bias_g3;
    pa.ei = ei; pa.cnt8 = cnt8;
    prep_all<<<PREP_BLKS, 256, 0, stream>>>(pa);

    // --- CSR build (scan merges per-XCD counts; scatter) ---
    scan1_kernel<<<NB, 256, 0, stream>>>(cnt8, cnt, incl, bsum);
    scan3_kernel<<<NB, 256, 0, stream>>>(cnt, incl, bsum, rowptr, woff, NB);
    scatter_idx_kernel<<<EB, 256, 0, stream>>>(ei, woff, csr_row, csr_col);

    // --- fused G1: [h1 | xw] = x @ [Wp1 | Wg0]^T (BK=64, WN=64 proven) ---
    gemm_mfma<128, 128, 64><<<dim3(5, MT), 256, 0, stream>>>(
        xb16, 512, Wp1t, 512, bias_g1, h1, 512, xw, 128, 512, NNODES, 512, 1, 1);

    // --- fused G2+G3: h2 = relu(h1@Wp2+bp2) in LDS; [lg|pe] = h2@[Wp3|W2]^T ---
    gemm_fused<64, 32, 128, 1, 0><<<dim3(1, MT64), 256, 0, stream>>>(
        h1, 512, Wp2t, 512, bp2, Wp3t, bias_g3, lg, 64, pe, 64, NNODES, 512);

    // --- per-edge weights (partial sums, no atomics) + tiny reduce ---
    edge_ew_gather<<<NEDGES / 32, 256, 0, stream>>>(lg, pe, csr_row, csr_col, ew_csr, part);
    ew_reduce_kernel<<<32, 256, 0, stream>>>(part, S);
    norm_deg_kernel<<<NB, 256, 0, stream>>>(rowptr, ew_csr, S, dis);
    csrw_kernel<<<NB, 256, 0, stream>>>(rowptr, csr_row, ew_csr, dis, csr_w);

    // --- GCN layer 0 aggregation (xw from fused G1) ---
    agg_kernel<<<25000, 128, 0, stream>>>((const unsigned*)xw, dis, rowptr, csr_row, csr_w, bg0, xj, 2 * HD);

    // --- GCN layer 1 ---
    gemm_mfma<64, 64, 32><<<dim3(2, MT64), 256, 0, stream>>>(
        xj, 2 * HD, Wg1t, 128, nullptr, xw, 128, nullptr, 0, BIGN, NNODES, 128, 0, 1);
    agg_kernel<<<25000, 128, 0, stream>>>((const unsigned*)xw, dis, rowptr, csr_row, csr_w, bg1, xj + HD, 2 * HD);

    // --- fused JK head: hid = relu(xj@Wl1+bl1) in LDS; out = hid@Wl2+bl2 ---
    gemm_fused<128, 64, 64, 0, 1><<<dim3(1, MT64), 256, 0, stream>>>(
        xj, 2 * HD, Wl1t, 256, bl1, Wl2t, bl2, out, 64, nullptr, 0, NNODES, 256);
}

// Round 10
// 476.149 us; speedup vs baseline: 1.0560x; 1.0560x over previous
//
#include <hip/hip_runtime.h>
#include <hip/hip_bf16.h>
#include <cmath>
#include <cstring>

#define NNODES 50000
#define NEDGES 800000
#define IND    512
#define HD     128
#define CD     64

typedef __bf16 bf16x8 __attribute__((ext_vector_type(8)));
typedef float  f32x4  __attribute__((ext_vector_type(4)));
typedef const __attribute__((address_space(1))) unsigned int* gu32p;
typedef __attribute__((address_space(3))) unsigned int* lu32p;

// ---------------- workspace layout (byte offsets) ----------------
static const size_t XJ_B   = 0;           // bf16 50000x256 (agg output; x_bf16 overlay early)
static const size_t HID_B  = 25600000;    // dead region; ew partial sums overlay (post-G1)
static const size_t H1_B   = 51200000;    // bf16 50000x512
static const size_t XW_B   = 102400000;   // bf16 50000x128
static const size_t CNT8_B = 115200000;   // int 8x50000 per-XCD degree counters (dead H2 area)
static const size_t LG_B   = 121600000;   // bf16 50000x64
static const size_t PE_B   = 128000000;   // bf16 50000x64
static const size_t WT_B   = 134400000;   // transposed bf16 weights + biases (~0.9MB)
static const size_t CSRR_B = 135300000;   // int 800000 (csr row index)
static const size_t EWC_B  = 138500000;   // fp32 800000 (ew in CSR order; normalized in place)
static const size_t CSRW_B = 141700000;   // int csr_col -> then fp32 csr_w (overlay)
static const size_t CNT_B  = 144900000;   // int 50000 (merged counts, written by scan1)
static const size_t S_B    = 145100000;   // 2 doubles (zeroed)
static const size_t RP_B   = 145100016;   // int 50001
static const size_t WOFF_B = 145300020;   // int 50000
static const size_t INCL_B = 145500020;   // int 50000
static const size_t BSUM_B = 145700020;   // int 256
static const size_t DIS_B  = 145701052;   // fp32 50000
// Round-9 lesson: device-scope atomics are memory-side RMW (per-XCD replicas
// changed NOTHING); their cost is latency, not locality. Hide it by
// interleaving atomics with BW-bound work in the SAME blocks (count in cast
// blocks; scatter in G1 blocks) instead of appending atomic-only block tails.

// weight sub-offsets (bytes within WT_B). Wp1t then Wg0t CONTIGUOUS (G1 fused
// Bt [640,512]); Wp3t then W2t=(Wp3@P)t CONTIGUOUS (G2G3 stage-2 Bt [128,64]).
static const size_t WP1T_O = 0;       // 512x512
static const size_t WG0T_O = 524288;  // 128x512
static const size_t WP2T_O = 655360;  // 64x512
static const size_t WP3T_O = 720896;  // 64x64
static const size_t W2T_O  = 729088;  // 64x64 (Wp3 @ relu(2*P0), transposed)
static const size_t WG1T_O = 737280;  // 128x128
static const size_t WL1T_O = 770048;  // 128x256
static const size_t WL2T_O = 835584;  // 64x128
static const size_t BG1_O  = 851968;  // fp32 640: [bp1 | zeros(128)]
static const size_t BG3_O  = 854528;  // fp32 128: [bp3 | bp3@P]

// ---------------- fused prep: x cast (+64 edge counts/block) + transposes --
struct WD { const float* s; __hip_bfloat16* d; int K; int N; };
struct PrepArgs {
    const float* x; __hip_bfloat16* xb;
    WD w[7];
    int bo[8];                       // cumulative TILE offsets per matrix
    const float* Wp3; const float* bp3; const float* P0; const float* bp1;
    __hip_bfloat16* W2t; float* bias_g1; float* bias_g3;
    const int* ei; int* cnt8;        // per-XCD degree counters
};
#define PREP_CAST_BLKS  12500
#define PREP_TP_BLKS    103
#define PREP_CMB_BLKS   20
#define PREP_BLKS (PREP_CAST_BLKS + PREP_TP_BLKS + PREP_CMB_BLKS)

__global__ __launch_bounds__(256) void prep_all(PrepArgs a)
{
    __shared__ __hip_bfloat16 tile[64][65];
    int b = blockIdx.x;
    int t = threadIdx.x;
    if (b < PREP_CAST_BLKS) {                 // ---- x cast + 64 edge counts ----
        // count: 64 edges/block, atomic latency hides under the streaming cast
        if (t < 64) {
            int e = b * 64 + t;               // 12500*64 == 800000 exactly
            int xcd = b & 7;
            atomicAdd(&a.cnt8[xcd * NNODES + a.ei[NEDGES + e]], 1);
        }
        int i = b * 256 + t;                  // 12500*256 == 50000*512/8 exactly
        const float4* p = (const float4*)a.x + (size_t)i * 2;
        float4 u = p[0], v = p[1];
        __hip_bfloat16 o[8] __attribute__((aligned(16)));
        o[0] = __float2bfloat16(u.x); o[1] = __float2bfloat16(u.y);
        o[2] = __float2bfloat16(u.z); o[3] = __float2bfloat16(u.w);
        o[4] = __float2bfloat16(v.x); o[5] = __float2bfloat16(v.y);
        o[6] = __float2bfloat16(v.z); o[7] = __float2bfloat16(v.w);
        *(int4*)(a.xb + (size_t)i * 8) = *(const int4*)o;
        return;
    }
    b -= PREP_CAST_BLKS;
    if (b < PREP_TP_BLKS) {                   // ---- LDS-tiled transpose+cast ----
        int m = 0;
        #pragma unroll
        for (int q = 1; q < 7; q++) if (b >= a.bo[q]) m = q;
        WD d = a.w[m];
        int q = b - a.bo[m];
        int ntn = d.N >> 6;                   // tiles across n
        int tk = (q / ntn) << 6;
        int tn = (q % ntn) << 6;
        int rr = t >> 6, cc = t & 63;
        #pragma unroll
        for (int r8 = 0; r8 < 16; r8++) {     // read: coalesced over n
            int row = r8 * 4 + rr;            // k within tile
            tile[row][cc] = __float2bfloat16(d.s[(size_t)(tk + row) * d.N + tn + cc]);
        }
        __syncthreads();
        #pragma unroll
        for (int r8 = 0; r8 < 16; r8++) {     // write: coalesced over k
            int n = r8 * 4 + rr;              // n within tile
            d.d[(size_t)(tn + n) * d.K + tk + cc] = tile[cc][n];
        }
        return;
    }
    b -= PREP_TP_BLKS;
    if (b < 16) {                             // ---- combine_p0 (20 blocks) ----
        int i = b * 256 + t;
        int k = i >> 6, n = i & 63;
        float s = 0.f;
        for (int j = 0; j < 64; j++)
            s += a.Wp3[k * 64 + j] * fmaxf(2.f * a.P0[j * 64 + n], 0.f);
        a.W2t[n * 64 + k] = __float2bfloat16(s);
    } else if (b == 16) {
        int n = t;
        if (n < 64) {
            float s = 0.f;
            for (int j = 0; j < 64; j++)
                s += a.bp3[j] * fmaxf(2.f * a.P0[j * 64 + n], 0.f);
            a.bias_g3[n] = a.bp3[n];
            a.bias_g3[64 + n] = s;
        }
    } else {
        int i = (b - 17) * 256 + t;           // 0..767
        if (i < 512) a.bias_g1[i] = a.bp1[i];
        else if (i < 640) a.bias_g1[i] = 0.f;
    }
}

// ---------------- bf16 MFMA GEMM: C = act(A[M,K] @ Bt[N,K]^T + bias) -------
// 4 waves, wave tile (BM/2) x WN, BN = 2*WN. K%64==0, N%BN==0.
// BK=64 via TWIN 32-wide tiles: both half-tiles' global_load_lds issued
// back-to-back (2x MLP per drain), ONE barrier, then MFMAs. Trailing barrier
// skipped on last K-step. Explicit dbuf REGRESSED (round 2); WN=32 for G1
// REGRESSED (round 7). SCATTER: when ei!=null, each block scatters ~410 CSR
// edges BEFORE its K-loop -- the 800k atomics+writes drain under the MFMA
// pipeline instead of costing a standalone latency-bound dispatch (round-9
// lesson: atomic cost is memory-side latency; hide it under compute).
template<int BM, int BN, int WN>
__global__ __launch_bounds__(256) void gemm_mfma(
    const __hip_bfloat16* __restrict__ Ab, int lda,
    const __hip_bfloat16* __restrict__ Bt, int ldb,
    const float* __restrict__ bias,
    void* __restrict__ Cout, int ldc,
    void* __restrict__ Cout2, int ldc2, int splitN,
    int M, int K, int do_relu, int out_bf16,
    const int* __restrict__ ei, int* __restrict__ woff,
    int* __restrict__ csr_row, int* __restrict__ csr_col)
{
    constexpr int BF = WN / 16;       // col frags per wave
    constexpr int MI = BM / 32;       // row frags per wave
    constexpr int APASS = BM / 64;    // A staging passes per 32-wide tile
    constexpr int BPASS = BN / 64;    // B staging passes per 32-wide tile
    __shared__ __bf16 As[2][BM * 32];
    __shared__ __bf16 Bs[2][BN * 32];

    const int NC = gridDim.x, NR = gridDim.y;
    int g = blockIdx.y * NC + blockIdx.x;

    // ---- fused CSR scatter (G1 only): issue before K-loop, drains under it
    if (ei) {
        const int EPB = 410;                          // 1955*410 >= 800000
        int e0 = g * EPB;
        int e1 = e0 + EPB; if (e1 > NEDGES) e1 = NEDGES;
        for (int e = e0 + threadIdx.x; e < e1; e += 256) {
            int r = ei[e];
            int c = ei[NEDGES + e];
            int p = atomicAdd(&woff[c], 1);
            csr_row[p] = r;
            csr_col[p] = c;
        }
    }

    int per = NC * 8;
    int nfull = (NR >> 3) * per;
    int rowt, colt;
    if (g < nfull) {
        int grp = g / per, rem = g % per;
        rowt = grp * 8 + (rem & 7);
        colt = rem >> 3;
    } else {
        int rem = g - nfull;
        int tail = NR - (NR >> 3) * 8;
        rowt = (NR >> 3) * 8 + rem % tail;
        colt = rem / tail;
    }

    const int t = threadIdx.x;
    const int row0 = rowt * BM;
    const int col0 = colt * BN;

    const int wv   = t >> 6;
    const int lane = t & 63;
    const int quad = lane >> 4;
    const int l16  = lane & 15;
    const int wrow = (wv >> 1) * (BM / 2);
    const int wcol = (wv & 1) * WN;

    const int subrow = lane >> 2;                          // 0..15
    const int kchunk = (lane & 3) ^ (subrow & 3);          // swizzled chunk
    const int subkg  = kchunk * 8;

    f32x4 acc[MI][BF] = {};

    for (int k0 = 0; k0 < K; k0 += 64) {
        #pragma unroll
        for (int h = 0; h < 2; h++) {
            int kh = k0 + h * 32;
            #pragma unroll
            for (int p = 0; p < APASS; p++) {
                int rowA = (p * 4 + wv) * 16 + subrow;
                const __hip_bfloat16* gp = Ab + (size_t)(row0 + rowA) * lda + kh + subkg;
                __builtin_amdgcn_global_load_lds((gu32p)(const void*)gp,
                    (lu32p)(void*)&As[h][(p * 4 + wv) * 512], 16, 0, 0);
            }
            #pragma unroll
            for (int p = 0; p < BPASS; p++) {
                int rowB = (p * 4 + wv) * 16 + subrow;
                const __hip_bfloat16* gp = Bt + (size_t)(col0 + rowB) * ldb + kh + subkg;
                __builtin_amdgcn_global_load_lds((gu32p)(const void*)gp,
                    (lu32p)(void*)&Bs[h][(p * 4 + wv) * 512], 16, 0, 0);
            }
        }
        __syncthreads();

        #pragma unroll
        for (int h = 0; h < 2; h++) {
            bf16x8 af[MI], bfr[BF];
            #pragma unroll
            for (int i = 0; i < MI; i++) {
                int R = wrow + i * 16 + l16;
                af[i] = *(const bf16x8*)&As[h][R * 32 + ((quad ^ (R & 3)) * 8)];
            }
            #pragma unroll
            for (int j = 0; j < BF; j++) {
                int R = wcol + j * 16 + l16;
                bfr[j] = *(const bf16x8*)&Bs[h][R * 32 + ((quad ^ (R & 3)) * 8)];
            }
            #pragma unroll
            for (int i = 0; i < MI; i++)
                #pragma unroll
                for (int j = 0; j < BF; j++)
                    acc[i][j] = __builtin_amdgcn_mfma_f32_16x16x32_bf16(af[i], bfr[j], acc[i][j], 0, 0, 0);
        }
        if (k0 + 64 < K) __syncthreads();
    }

    #pragma unroll
    for (int i = 0; i < MI; i++) {
        #pragma unroll
        for (int j = 0; j < BF; j++) {
            int n = col0 + wcol + j * 16 + l16;
            bool second = (n >= splitN);
            float bv = bias ? bias[n] : 0.f;
            #pragma unroll
            for (int reg = 0; reg < 4; reg++) {
                int m = row0 + wrow + i * 16 + quad * 4 + reg;
                if (m >= M) continue;
                float v = acc[i][j][reg] + bv;
                if (do_relu && !second) v = fmaxf(v, 0.f);
                if (second)
                    ((__hip_bfloat16*)Cout2)[(size_t)m * ldc2 + (n - splitN)] = __float2bfloat16(v);
                else if (out_bf16)
                    ((__hip_bfloat16*)Cout)[(size_t)m * ldc + n] = __float2bfloat16(v);
                else
                    ((float*)Cout)[(size_t)m * ldc + n] = v;
            }
        }
    }
}

// ---------------- fused 2-stage GEMM ---------------------------------------
// Stage 1: T[64,BN1] = relu(A[M,K1] @ B1t[BN1,K1]^T + bias1) held in LDS.
// Stage 2: Out[64,N2] = T @ B2t[N2,BN1]^T + bias2.  (see round-4 notes)
template<int BN1, int WN1, int N2, int SPLIT2, int OUT2F32>
__global__ __launch_bounds__(256) void gemm_fused(
    const __hip_bfloat16* __restrict__ Ab, int lda,
    const __hip_bfloat16* __restrict__ B1t, int ldb1,
    const float* __restrict__ bias1,
    const __hip_bfloat16* __restrict__ B2t,
    const float* __restrict__ bias2,
    void* __restrict__ Out1, int ldo1,
    void* __restrict__ Out2, int ldo2,
    int M, int K1)
{
    constexpr int BF1 = WN1 / 16;
    constexpr int BPASS1 = BN1 / 64;
    constexpr int K2H = BN1 / 32;        // stage-2 K chunks of 32
    constexpr int WN2 = N2 / 2;
    constexpr int BF2 = WN2 / 16;
    constexpr int P2 = N2 / 64;
    __shared__ __bf16 L1[4096 + BN1 * 64];   // [As(2x2048) | Bs1(2 x BN1*32)]
    __shared__ __bf16 Bs2[8192];             // K2H x N2*32 (= BN1*N2 = 8192 both cfgs)

    const int t = threadIdx.x;
    const int row0 = blockIdx.y * 64;
    const int wv   = t >> 6;
    const int lane = t & 63;
    const int quad = lane >> 4;
    const int l16  = lane & 15;
    const int wrow1 = (wv >> 1) * 32;
    const int wcol1 = (wv & 1) * WN1;
    const int subrow = lane >> 2;
    const int subkg  = ((lane & 3) ^ (subrow & 3)) * 8;

    // stage B2 once (drains with first K-loop barrier)
    #pragma unroll
    for (int hh = 0; hh < K2H; hh++)
        #pragma unroll
        for (int p = 0; p < P2; p++) {
            int rowB = (p * 4 + wv) * 16 + subrow;
            const __hip_bfloat16* gp = B2t + (size_t)rowB * BN1 + hh * 32 + subkg;
            __builtin_amdgcn_global_load_lds((gu32p)(const void*)gp,
                (lu32p)(void*)&Bs2[hh * (N2 * 32) + (p * 4 + wv) * 512], 16, 0, 0);
        }

    f32x4 acc1[2][BF1] = {};
    for (int k0 = 0; k0 < K1; k0 += 64) {
        #pragma unroll
        for (int h = 0; h < 2; h++) {
            int kh = k0 + h * 32;
            {
                int rowA = wv * 16 + subrow;
                const __hip_bfloat16* gp = Ab + (size_t)(row0 + rowA) * lda + kh + subkg;
                __builtin_amdgcn_global_load_lds((gu32p)(const void*)gp,
                    (lu32p)(void*)&L1[h * 2048 + wv * 512], 16, 0, 0);
            }
            #pragma unroll
            for (int p = 0; p < BPASS1; p++) {
                int rowB = (p * 4 + wv) * 16 + subrow;
                const __hip_bfloat16* gp = B1t + (size_t)rowB * ldb1 + kh + subkg;
                __builtin_amdgcn_global_load_lds((gu32p)(const void*)gp,
                    (lu32p)(void*)&L1[4096 + h * (BN1 * 32) + (p * 4 + wv) * 512], 16, 0, 0);
            }
        }
        __syncthreads();
        #pragma unroll
        for (int h = 0; h < 2; h++) {
            bf16x8 af[2], bfr[BF1];
            #pragma unroll
            for (int i = 0; i < 2; i++) {
                int R = wrow1 + i * 16 + l16;
                af[i] = *(const bf16x8*)&L1[h * 2048 + R * 32 + ((quad ^ (R & 3)) * 8)];
            }
            #pragma unroll
            for (int j = 0; j < BF1; j++) {
                int R = wcol1 + j * 16 + l16;
                bfr[j] = *(const bf16x8*)&L1[4096 + h * (BN1 * 32) + R * 32 + ((quad ^ (R & 3)) * 8)];
            }
            #pragma unroll
            for (int i = 0; i < 2; i++)
                #pragma unroll
                for (int j = 0; j < BF1; j++)
                    acc1[i][j] = __builtin_amdgcn_mfma_f32_16x16x32_bf16(af[i], bfr[j], acc1[i][j], 0, 0, 0);
        }
        __syncthreads();   // ALWAYS: T overlays As/Bs next (or next stage)
    }

    // T = relu(acc1 + bias1) -> bf16 into L1 (swizzled layout, overlay)
    #pragma unroll
    for (int i = 0; i < 2; i++)
        #pragma unroll
        for (int j = 0; j < BF1; j++) {
            int n1 = wcol1 + j * 16 + l16;
            float bv = bias1[n1];
            int h = n1 >> 5, kk = n1 & 31;
            int q = kk >> 3, pp = kk & 7;
            #pragma unroll
            for (int reg = 0; reg < 4; reg++) {
                int r = wrow1 + i * 16 + quad * 4 + reg;
                float v = fmaxf(acc1[i][j][reg] + bv, 0.f);
                __hip_bfloat16 hb = __float2bfloat16(v);
                unsigned short us; memcpy(&us, &hb, 2);
                *(unsigned short*)&L1[h * 2048 + r * 32 + ((q ^ (r & 3)) * 8) + pp] = us;
            }
        }
    __syncthreads();

    // stage 2
    const int wrow2 = (wv >> 1) * 32;
    const int wcol2 = (wv & 1) * WN2;
    f32x4 acc2[2][BF2] = {};
    #pragma unroll
    for (int hh = 0; hh < K2H; hh++) {
        bf16x8 af2[2], bf2[BF2];
        #pragma unroll
        for (int i = 0; i < 2; i++) {
            int R = wrow2 + i * 16 + l16;
            af2[i] = *(const bf16x8*)&L1[hh * 2048 + R * 32 + ((quad ^ (R & 3)) * 8)];
        }
        #pragma unroll
        for (int j = 0; j < BF2; j++) {
            int R = wcol2 + j * 16 + l16;
            bf2[j] = *(const bf16x8*)&Bs2[hh * (N2 * 32) + R * 32 + ((quad ^ (R & 3)) * 8)];
        }
        #pragma unroll
        for (int i = 0; i < 2; i++)
            #pragma unroll
            for (int j = 0; j < BF2; j++)
                acc2[i][j] = __builtin_amdgcn_mfma_f32_16x16x32_bf16(af2[i], bf2[j], acc2[i][j], 0, 0, 0);
    }

    #pragma unroll
    for (int i = 0; i < 2; i++)
        #pragma unroll
        for (int j = 0; j < BF2; j++) {
            int n2 = wcol2 + j * 16 + l16;
            float bv = bias2[n2];
            #pragma unroll
            for (int reg = 0; reg < 4; reg++) {
                int m = row0 + wrow2 + i * 16 + quad * 4 + reg;
                if (m >= M) continue;
                float v = acc2[i][j][reg] + bv;
                if (SPLIT2) {
                    if (n2 < 64)
                        ((__hip_bfloat16*)Out1)[(size_t)m * ldo1 + n2] = __float2bfloat16(v);
                    else
                        ((__hip_bfloat16*)Out2)[(size_t)m * ldo2 + (n2 - 64)] = __float2bfloat16(v);
                } else if (OUT2F32) {
                    ((float*)Out1)[(size_t)m * ldo1 + n2] = v;
                } else {
                    ((__hip_bfloat16*)Out1)[(size_t)m * ldo1 + n2] = __float2bfloat16(v);
                }
            }
        }
}

// ---------------- CSR build (count fused into prep; scatter fused into G1) -
// scan1 merges the 8 per-XCD count replicas, stores merged cnt, scans.
__global__ __launch_bounds__(256) void scan1_kernel(
    const int* __restrict__ cnt8, int* __restrict__ cnt,
    int* __restrict__ incl, int* __restrict__ bsum)
{
    __shared__ int s[256];
    int t = threadIdx.x;
    int i = blockIdx.x * 256 + t;
    int v = 0;
    if (i < NNODES) {
        #pragma unroll
        for (int x = 0; x < 8; x++) v += cnt8[x * NNODES + i];
        cnt[i] = v;
    }
    s[t] = v;
    __syncthreads();
    for (int off = 1; off < 256; off <<= 1) {
        int u = (t >= off) ? s[t - off] : 0;
        __syncthreads();
        s[t] += u;
        __syncthreads();
    }
    if (i < NNODES) incl[i] = s[t];
    if (t == 255) bsum[blockIdx.x] = s[255];
}

// scan3 with scan2 folded in (identical integer math to scan2+scan3 pair).
__global__ __launch_bounds__(256) void scan3_kernel(
    const int* __restrict__ cnt, const int* __restrict__ incl,
    const int* __restrict__ bsum, int* __restrict__ rowptr,
    int* __restrict__ woff, int nb)
{
    __shared__ int s[256];
    int t = threadIdx.x;
    int v = (t < nb) ? bsum[t] : 0;
    s[t] = v;
    __syncthreads();
    for (int off = 1; off < 256; off <<= 1) {
        int u = (t >= off) ? s[t - off] : 0;
        __syncthreads();
        s[t] += u;
        __syncthreads();
    }
    int off = s[blockIdx.x] - bsum[blockIdx.x];   // exclusive prefix of own block
    int i = blockIdx.x * 256 + t;
    if (i >= NNODES) return;
    int r = incl[i] - cnt[i] + off;
    rowptr[i] = r;
    woff[i] = r;
    if (i == NNODES - 1) rowptr[NNODES] = incl[i] + off;
}

// ---------------- edge weight: 8 lanes per edge; partial sums NO atomics ---
// Round-6 lesson: 50000 same-address double atomicAdds serialized (~600us);
// per-block partials (plain stores) + tiny reduce instead.
__global__ __launch_bounds__(256) void edge_ew_gather(
    const __hip_bfloat16* __restrict__ lg, const __hip_bfloat16* __restrict__ pe,
    const int* __restrict__ csr_row, const int* __restrict__ csr_col,
    float* __restrict__ ew_csr, double* __restrict__ part)
{
    const int tid = threadIdx.x;
    const int sub = tid & 7;
    const int e = blockIdx.x * 32 + (tid >> 3);   // 25000*32 == 800000 exactly
    int r = csr_row[e];
    int c = csr_col[e];
    bf16x8 a = *(const bf16x8*)(lg + (size_t)r * CD + sub * 8);
    bf16x8 b = *(const bf16x8*)(pe + (size_t)c * CD + sub * 8);
    float acc = 0.f;
    #pragma unroll
    for (int u = 0; u < 8; u++)
        acc += (float)a[u] * (float)b[u];
    acc += __shfl_xor(acc, 1);
    acc += __shfl_xor(acc, 2);
    acc += __shfl_xor(acc, 4);
    if (sub == 0) ew_csr[e] = acc;

    double s1 = (sub == 0) ? (double)acc : 0.0;
    double s2 = (sub == 0) ? (double)acc * (double)acc : 0.0;
    #pragma unroll
    for (int off = 8; off < 64; off <<= 1) {      // combine the 8 sub0 lanes/wave
        s1 += __shfl_xor(s1, off);
        s2 += __shfl_xor(s2, off);
    }
    __shared__ double sh1[4], sh2[4];
    if ((tid & 63) == 0) { sh1[tid >> 6] = s1; sh2[tid >> 6] = s2; }
    __syncthreads();
    if (tid == 0) {
        part[2 * blockIdx.x]     = sh1[0] + sh1[1] + sh1[2] + sh1[3];
        part[2 * blockIdx.x + 1] = sh2[0] + sh2[1] + sh2[2] + sh2[3];
    }
}

// reduce the 25000 partial pairs into S (64 total atomics -- no contention)
__global__ __launch_bounds__(256) void ew_reduce_kernel(
    const double* __restrict__ part, double* __restrict__ S)
{
    const int tid = threadIdx.x;
    double s1 = 0.0, s2 = 0.0;
    for (int i = blockIdx.x * 256 + tid; i < 25000; i += gridDim.x * 256) {
        s1 += part[2 * i];
        s2 += part[2 * i + 1];
    }
    __shared__ double sh1[256], sh2[256];
    sh1[tid] = s1; sh2[tid] = s2;
    __syncthreads();
    for (int s = 128; s > 0; s >>= 1) {
        if (tid < s) { sh1[tid] += sh1[tid + s]; sh2[tid] += sh2[tid + s]; }
        __syncthreads();
    }
    if (tid == 0) {
        atomicAdd(&S[0], sh1[0]);
        atomicAdd(&S[1], sh2[0]);
    }
}

// per node: normalize segment in place, deg = segment sum, dis = rsqrt(deg+1).
__global__ __launch_bounds__(256) void norm_deg_kernel(
    const int* __restrict__ rowptr, float* __restrict__ ew_csr,
    const double* __restrict__ S, float* __restrict__ dis)
{
    int n = blockIdx.x * 256 + threadIdx.x;
    if (n >= NNODES) return;
    const double Ed = (double)NEDGES;
    double meand = S[0] / Ed;
    double var = (S[1] - S[0] * S[0] / Ed) / (Ed - 1.0);
    float mean = (float)meand;
    float alpha = (float)sqrt(1e-4 / var);
    int s = rowptr[n], e = rowptr[n + 1];
    float sum = 0.f;
    for (int j = s; j < e; j++) {
        float w = (ew_csr[j] - mean) * alpha + 1.0f;
        ew_csr[j] = w;
        sum += w;
    }
    float d = sum + 1.0f;                       // self-loop weight 1
    dis[n] = (d > 0.f) ? rsqrtf(d) : 0.f;
}

// per node: csr_w[j] = dis[row]*w*dis[n]  (csr_w overlays the dead csr_col)
__global__ __launch_bounds__(256) void csrw_kernel(
    const int* __restrict__ rowptr, const int* __restrict__ csr_row,
    const float* __restrict__ ew_csr, const float* __restrict__ dis,
    float* __restrict__ csr_w)
{
    int n = blockIdx.x * 256 + threadIdx.x;
    if (n >= NNODES) return;
    float dn = dis[n];
    int s = rowptr[n], e = rowptr[n + 1];
    for (int j = s; j < e; j++)
        csr_w[j] = dis[csr_row[j]] * ew_csr[j] * dn;
}

// ---------------- weighted aggregation, MLP-optimized ----------------------
__global__ __launch_bounds__(128) void agg_kernel(
    const unsigned* __restrict__ xw32, const float* __restrict__ dis,
    const int* __restrict__ rowptr, const int* __restrict__ csr_row,
    const float* __restrict__ csr_w, const float* __restrict__ bias,
    __hip_bfloat16* __restrict__ out, int ldo)
{
    const int wv = threadIdx.x >> 6, lane = threadIdx.x & 63;
    const int n = blockIdx.x * 2 + wv;
    if (n >= NNODES) return;
    float dn = dis[n];
    unsigned v0 = xw32[(size_t)n * 64 + lane];
    float aL = dn * dn * __uint_as_float(v0 << 16);
    float aH = dn * dn * __uint_as_float(v0 & 0xffff0000u);
    int s = rowptr[n], e = rowptr[n + 1];
    int j = s;
    for (; j + 4 <= e; j += 4) {
        int r0 = csr_row[j], r1 = csr_row[j + 1];
        int r2 = csr_row[j + 2], r3 = csr_row[j + 3];
        float w0 = csr_w[j], w1 = csr_w[j + 1];
        float w2 = csr_w[j + 2], w3 = csr_w[j + 3];
        unsigned g0 = xw32[(size_t)r0 * 64 + lane];
        unsigned g1 = xw32[(size_t)r1 * 64 + lane];
        unsigned g2 = xw32[(size_t)r2 * 64 + lane];
        unsigned g3 = xw32[(size_t)r3 * 64 + lane];
        aL = fmaf(w0, __uint_as_float(g0 << 16), aL);
        aH = fmaf(w0, __uint_as_float(g0 & 0xffff0000u), aH);
        aL = fmaf(w1, __uint_as_float(g1 << 16), aL);
        aH = fmaf(w1, __uint_as_float(g1 & 0xffff0000u), aH);
        aL = fmaf(w2, __uint_as_float(g2 << 16), aL);
        aH = fmaf(w2, __uint_as_float(g2 & 0xffff0000u), aH);
        aL = fmaf(w3, __uint_as_float(g3 << 16), aL);
        aH = fmaf(w3, __uint_as_float(g3 & 0xffff0000u), aH);
    }
    for (; j < e; j++) {
        int r = csr_row[j];
        float w = csr_w[j];
        unsigned g = xw32[(size_t)r * 64 + lane];
        aL = fmaf(w, __uint_as_float(g << 16), aL);
        aH = fmaf(w, __uint_as_float(g & 0xffff0000u), aH);
    }
    float2 b = *(const float2*)(bias + 2 * lane);
    aL = fmaxf(aL + b.x, 0.f);
    aH = fmaxf(aH + b.y, 0.f);
    __hip_bfloat16 bl = __float2bfloat16(aL), bh = __float2bfloat16(aH);
    unsigned short ul, uh;
    memcpy(&ul, &bl, 2); memcpy(&uh, &bh, 2);
    unsigned o = (unsigned)ul | ((unsigned)uh << 16);
    *(unsigned*)(out + (size_t)n * ldo + 2 * lane) = o;
}

// ---------------- launch --------------------------------------------------
extern "C" void kernel_launch(void* const* d_in, const int* in_sizes, int n_in,
                              void* d_out, int out_size, void* d_ws, size_t ws_size,
                              hipStream_t stream)
{
    const float* x   = (const float*)d_in[0];
    const int*   ei  = (const int*)d_in[1];
    const float* Wp1 = (const float*)d_in[2];
    const float* bp1 = (const float*)d_in[3];
    const float* Wp2 = (const float*)d_in[4];
    const float* bp2 = (const float*)d_in[5];
    const float* Wp3 = (const float*)d_in[6];
    const float* bp3 = (const float*)d_in[7];
    const float* P0  = (const float*)d_in[8];
    const float* Wg0 = (const float*)d_in[9];
    const float* bg0 = (const float*)d_in[10];
    const float* Wg1 = (const float*)d_in[11];
    const float* bg1 = (const float*)d_in[12];
    // d_in[13], d_in[14] = Wg2/bg2: dead in reference
    const float* Wl1 = (const float*)d_in[15];
    const float* bl1 = (const float*)d_in[16];
    const float* Wl2 = (const float*)d_in[17];
    const float* bl2 = (const float*)d_in[18];
    float* out = (float*)d_out;

    char* wsb = (char*)d_ws;
    __hip_bfloat16* xj     = (__hip_bfloat16*)(wsb + XJ_B);
    __hip_bfloat16* xb16   = (__hip_bfloat16*)(wsb + XJ_B);  // x bf16 overlay (early)
    double*         part   = (double*)(wsb + HID_B);         // ew partials (post-G1)
    __hip_bfloat16* h1     = (__hip_bfloat16*)(wsb + H1_B);
    __hip_bfloat16* xw     = (__hip_bfloat16*)(wsb + XW_B);
    int*            cnt8   = (int*)(wsb + CNT8_B);           // per-XCD degree counters
    __hip_bfloat16* lg     = (__hip_bfloat16*)(wsb + LG_B);
    __hip_bfloat16* pe     = (__hip_bfloat16*)(wsb + PE_B);
    int*            csr_row= (int*)(wsb + CSRR_B);
    float*          ew_csr = (float*)(wsb + EWC_B);
    int*            csr_col= (int*)(wsb + CSRW_B);   // overlays csr_w (dead until csrw_kernel)
    float*          csr_w  = (float*)(wsb + CSRW_B);
    int*            cnt    = (int*)(wsb + CNT_B);
    double*         S      = (double*)(wsb + S_B);
    int*            rowptr = (int*)(wsb + RP_B);
    int*            woff   = (int*)(wsb + WOFF_B);
    int*            incl   = (int*)(wsb + INCL_B);
    int*            bsum   = (int*)(wsb + BSUM_B);
    float*          dis    = (float*)(wsb + DIS_B);

    __hip_bfloat16* Wp1t = (__hip_bfloat16*)(wsb + WT_B + WP1T_O);
    __hip_bfloat16* Wg0t = (__hip_bfloat16*)(wsb + WT_B + WG0T_O);
    __hip_bfloat16* Wp2t = (__hip_bfloat16*)(wsb + WT_B + WP2T_O);
    __hip_bfloat16* Wp3t = (__hip_bfloat16*)(wsb + WT_B + WP3T_O);
    __hip_bfloat16* W2t  = (__hip_bfloat16*)(wsb + WT_B + W2T_O);
    __hip_bfloat16* Wg1t = (__hip_bfloat16*)(wsb + WT_B + WG1T_O);
    __hip_bfloat16* Wl1t = (__hip_bfloat16*)(wsb + WT_B + WL1T_O);
    __hip_bfloat16* Wl2t = (__hip_bfloat16*)(wsb + WT_B + WL2T_O);
    float*          bias_g1 = (float*)(wsb + WT_B + BG1_O);
    float*          bias_g3 = (float*)(wsb + WT_B + BG3_O);

    const int NB = (NNODES + 255) / 256;            // 196
    const int MT  = (NNODES + 127) / 128;           // 391 row tiles (BM=128)
    const int MT64 = (NNODES + 63) / 64;            // 782 row tiles (BM=64)
    const int BIGN = 1 << 30;

    hipMemsetAsync(wsb + CNT8_B, 0, 8 * NNODES * sizeof(int), stream);
    hipMemsetAsync(wsb + S_B, 0, 16, stream);

    // --- fused prep: x cast (+edge counts interleaved) + transposes + P0 ---
    PrepArgs pa;
    pa.x = x; pa.xb = xb16;
    pa.w[0] = { Wp1, Wp1t, 512, 512 };
    pa.w[1] = { Wg0, Wg0t, 512, 128 };
    pa.w[2] = { Wp2, Wp2t, 512,  64 };
    pa.w[3] = { Wp3, Wp3t,  64,  64 };
    pa.w[4] = { Wg1, Wg1t, 128, 128 };
    pa.w[5] = { Wl1, Wl1t, 256, 128 };
    pa.w[6] = { Wl2, Wl2t, 128,  64 };
    // 64x64 tiles per matrix: 64,16,8,1,4,8,2 (cumulative below)
    pa.bo[0] = 0;  pa.bo[1] = 64; pa.bo[2] = 80; pa.bo[3] = 88;
    pa.bo[4] = 89; pa.bo[5] = 93; pa.bo[6] = 101; pa.bo[7] = 103;
    pa.Wp3 = Wp3; pa.bp3 = bp3; pa.P0 = P0; pa.bp1 = bp1;
    pa.W2t = W2t; pa.bias_g1 = bias_g1; pa.bias_g3 = bias_g3;
    pa.ei = ei; pa.cnt8 = cnt8;
    prep_all<<<PREP_BLKS, 256, 0, stream>>>(pa);

    // --- CSR scans (scatter is fused into G1) ---
    scan1_kernel<<<NB, 256, 0, stream>>>(cnt8, cnt, incl, bsum);
    scan3_kernel<<<NB, 256, 0, stream>>>(cnt, incl, bsum, rowptr, woff, NB);

    // --- fused G1: [h1 | xw] = x @ [Wp1 | Wg0]^T  + CSR scatter ---
    gemm_mfma<128, 128, 64><<<dim3(5, MT), 256, 0, stream>>>(
        xb16, 512, Wp1t, 512, bias_g1, h1, 512, xw, 128, 512, NNODES, 512, 1, 1,
        ei, woff, csr_row, csr_col);

    // --- fused G2+G3: h2 = relu(h1@Wp2+bp2) in LDS; [lg|pe] = h2@[Wp3|W2]^T ---
    gemm_fused<64, 32, 128, 1, 0><<<dim3(1, MT64), 256, 0, stream>>>(
        h1, 512, Wp2t, 512, bp2, Wp3t, bias_g3, lg, 64, pe, 64, NNODES, 512);

    // --- per-edge weights (partial sums, no atomics) + tiny reduce ---
    edge_ew_gather<<<NEDGES / 32, 256, 0, stream>>>(lg, pe, csr_row, csr_col, ew_csr, part);
    ew_reduce_kernel<<<32, 256, 0, stream>>>(part, S);
    norm_deg_kernel<<<NB, 256, 0, stream>>>(rowptr, ew_csr, S, dis);
    csrw_kernel<<<NB, 256, 0, stream>>>(rowptr, csr_row, ew_csr, dis, csr_w);

    // --- GCN layer 0 aggregation (xw from fused G1) ---
    agg_kernel<<<25000, 128, 0, stream>>>((const unsigned*)xw, dis, rowptr, csr_row, csr_w, bg0, xj, 2 * HD);

    // --- GCN layer 1 ---
    gemm_mfma<64, 64, 32><<<dim3(2, MT64), 256, 0, stream>>>(
        xj, 2 * HD, Wg1t, 128, nullptr, xw, 128, nullptr, 0, BIGN, NNODES, 128, 0, 1,
        nullptr, nullptr, nullptr, nullptr);
    agg_kernel<<<25000, 128, 0, stream>>>((const unsigned*)xw, dis, rowptr, csr_row, csr_w, bg1, xj + HD, 2 * HD);

    // --- fused JK head: hid = relu(xj@Wl1+bl1) in LDS; out = hid@Wl2+bl2 ---
    gemm_fused<128, 64, 64, 0, 1><<<dim3(1, MT64), 256, 0, stream>>>(
        xj, 2 * HD, Wl1t, 256, bl1, Wl2t, bl2, out, 64, nullptr, 0, NNODES, 256);
}

// Round 12
// 473.451 us; speedup vs baseline: 1.0621x; 1.0057x over previous
//
#include <hip/hip_runtime.h>
#include <hip/hip_bf16.h>
#include <cmath>
#include <cstring>

#define NNODES 50000
#define NEDGES 800000
#define IND    512
#define HD     128
#define CD     64

typedef __bf16 bf16x8 __attribute__((ext_vector_type(8)));
typedef float  f32x4  __attribute__((ext_vector_type(4)));
typedef const __attribute__((address_space(1))) unsigned int* gu32p;
typedef __attribute__((address_space(3))) unsigned int* lu32p;

// ---------------- workspace layout (byte offsets) ----------------
static const size_t XJ_B   = 0;           // bf16 50000x256 (agg output; x_bf16 overlay early)
static const size_t HID_B  = 25600000;    // dead region; ew partial sums overlay (post-G1)
static const size_t H1_B   = 51200000;    // bf16 50000x512
static const size_t XW_B   = 102400000;   // bf16 50000x128
static const size_t CNT8_B = 115200000;   // int 8x50000 per-XCD degree counters (dead H2 area)
static const size_t LG_B   = 121600000;   // bf16 50000x64
static const size_t PE_B   = 128000000;   // bf16 50000x64
static const size_t WT_B   = 134400000;   // transposed bf16 weights + biases (~0.9MB)
static const size_t CSRRC_B= 135300000;   // int2 800000 (row,col) pairs -- 6.4MB
static const size_t EWC_B  = 141700000;   // fp32 800000 ew -> normalized -> final csr_w IN PLACE
static const size_t CNT_B  = 144900000;   // int 50000 (merged counts, written by scan1)
static const size_t S_B    = 145100000;   // 2 doubles (zeroed)
static const size_t RP_B   = 145100016;   // int 50001
static const size_t WOFF_B = 145300020;   // int 50000
static const size_t INCL_B = 145500020;   // int 50000
static const size_t BSUM_B = 145700020;   // int 256
static const size_t DIS_B  = 145701052;   // fp32 50000
// Round-10 lesson: CSR scatter as two 4B stores at random p dirtied 2x64B
// lines/edge (+81MB WRITE on G1). int2-paired single 8B store halves that;
// scatter moved to G1 EPILOGUE (prologue's atomic-return dependency delayed
// every block's first MFMA -- MfmaUtil 17.7->11.1). csr_w now updates ew
// in place (same j), freeing the old csr_w region for the int2 array.
// Round-9 lesson: atomics are memory-side RMW; hide latency under BW/compute
// work in the SAME blocks, never as atomic-only block tails.

// weight sub-offsets (bytes within WT_B). Wp1t then Wg0t CONTIGUOUS (G1 fused
// Bt [640,512]); Wp3t then W2t=(Wp3@P)t CONTIGUOUS (G2G3 stage-2 Bt [128,64]).
static const size_t WP1T_O = 0;       // 512x512
static const size_t WG0T_O = 524288;  // 128x512
static const size_t WP2T_O = 655360;  // 64x512
static const size_t WP3T_O = 720896;  // 64x64
static const size_t W2T_O  = 729088;  // 64x64 (Wp3 @ relu(2*P0), transposed)
static const size_t WG1T_O = 737280;  // 128x128
static const size_t WL1T_O = 770048;  // 128x256
static const size_t WL2T_O = 835584;  // 64x128
static const size_t BG1_O  = 851968;  // fp32 640: [bp1 | zeros(128)]
static const size_t BG3_O  = 854528;  // fp32 128: [bp3 | bp3@P]

// ---------------- fused prep: x cast (+64 edge counts/block) + transposes --
struct WD { const float* s; __hip_bfloat16* d; int K; int N; };
struct PrepArgs {
    const float* x; __hip_bfloat16* xb;
    WD w[7];
    int bo[8];                       // cumulative TILE offsets per matrix
    const float* Wp3; const float* bp3; const float* P0; const float* bp1;
    __hip_bfloat16* W2t; float* bias_g1; float* bias_g3;
    const int* ei; int* cnt8;        // per-XCD degree counters
};
#define PREP_CAST_BLKS  12500
#define PREP_TP_BLKS    103
#define PREP_CMB_BLKS   20
#define PREP_BLKS (PREP_CAST_BLKS + PREP_TP_BLKS + PREP_CMB_BLKS)

__global__ __launch_bounds__(256) void prep_all(PrepArgs a)
{
    __shared__ __hip_bfloat16 tile[64][65];
    int b = blockIdx.x;
    int t = threadIdx.x;
    if (b < PREP_CAST_BLKS) {                 // ---- x cast + 64 edge counts ----
        // count: 64 edges/block, atomic latency hides under the streaming cast
        if (t < 64) {
            int e = b * 64 + t;               // 12500*64 == 800000 exactly
            int xcd = b & 7;
            atomicAdd(&a.cnt8[xcd * NNODES + a.ei[NEDGES + e]], 1);
        }
        int i = b * 256 + t;                  // 12500*256 == 50000*512/8 exactly
        const float4* p = (const float4*)a.x + (size_t)i * 2;
        float4 u = p[0], v = p[1];
        __hip_bfloat16 o[8] __attribute__((aligned(16)));
        o[0] = __float2bfloat16(u.x); o[1] = __float2bfloat16(u.y);
        o[2] = __float2bfloat16(u.z); o[3] = __float2bfloat16(u.w);
        o[4] = __float2bfloat16(v.x); o[5] = __float2bfloat16(v.y);
        o[6] = __float2bfloat16(v.z); o[7] = __float2bfloat16(v.w);
        *(int4*)(a.xb + (size_t)i * 8) = *(const int4*)o;
        return;
    }
    b -= PREP_CAST_BLKS;
    if (b < PREP_TP_BLKS) {                   // ---- LDS-tiled transpose+cast ----
        int m = 0;
        #pragma unroll
        for (int q = 1; q < 7; q++) if (b >= a.bo[q]) m = q;
        WD d = a.w[m];
        int q = b - a.bo[m];
        int ntn = d.N >> 6;                   // tiles across n
        int tk = (q / ntn) << 6;
        int tn = (q % ntn) << 6;
        int rr = t >> 6, cc = t & 63;
        #pragma unroll
        for (int r8 = 0; r8 < 16; r8++) {     // read: coalesced over n
            int row = r8 * 4 + rr;            // k within tile
            tile[row][cc] = __float2bfloat16(d.s[(size_t)(tk + row) * d.N + tn + cc]);
        }
        __syncthreads();
        #pragma unroll
        for (int r8 = 0; r8 < 16; r8++) {     // write: coalesced over k
            int n = r8 * 4 + rr;              // n within tile
            d.d[(size_t)(tn + n) * d.K + tk + cc] = tile[cc][n];
        }
        return;
    }
    b -= PREP_TP_BLKS;
    if (b < 16) {                             // ---- combine_p0 (20 blocks) ----
        int i = b * 256 + t;
        int k = i >> 6, n = i & 63;
        float s = 0.f;
        for (int j = 0; j < 64; j++)
            s += a.Wp3[k * 64 + j] * fmaxf(2.f * a.P0[j * 64 + n], 0.f);
        a.W2t[n * 64 + k] = __float2bfloat16(s);
    } else if (b == 16) {
        int n = t;
        if (n < 64) {
            float s = 0.f;
            for (int j = 0; j < 64; j++)
                s += a.bp3[j] * fmaxf(2.f * a.P0[j * 64 + n], 0.f);
            a.bias_g3[n] = a.bp3[n];
            a.bias_g3[64 + n] = s;
        }
    } else {
        int i = (b - 17) * 256 + t;           // 0..767
        if (i < 512) a.bias_g1[i] = a.bp1[i];
        else if (i < 640) a.bias_g1[i] = 0.f;
    }
}

// ---------------- bf16 MFMA GEMM: C = act(A[M,K] @ Bt[N,K]^T + bias) -------
// 4 waves, wave tile (BM/2) x WN, BN = 2*WN. K%64==0, N%BN==0.
// BK=64 via TWIN 32-wide tiles; one barrier per K-step; trailing barrier
// skipped. Explicit dbuf REGRESSED (round 2); WN=32 for G1 REGRESSED (r7).
// SCATTER (G1 only): in the EPILOGUE (prologue placement collapsed MfmaUtil
// 17.7->11.1, round 10); int2 (8B) stores halve random-write line count;
// both atomics issued before dependent stores (2-deep MLP).
template<int BM, int BN, int WN>
__global__ __launch_bounds__(256) void gemm_mfma(
    const __hip_bfloat16* __restrict__ Ab, int lda,
    const __hip_bfloat16* __restrict__ Bt, int ldb,
    const float* __restrict__ bias,
    void* __restrict__ Cout, int ldc,
    void* __restrict__ Cout2, int ldc2, int splitN,
    int M, int K, int do_relu, int out_bf16,
    const int* __restrict__ ei, int* __restrict__ woff,
    int* __restrict__ csr_rc)
{
    constexpr int BF = WN / 16;       // col frags per wave
    constexpr int MI = BM / 32;       // row frags per wave
    constexpr int APASS = BM / 64;    // A staging passes per 32-wide tile
    constexpr int BPASS = BN / 64;    // B staging passes per 32-wide tile
    __shared__ __bf16 As[2][BM * 32];
    __shared__ __bf16 Bs[2][BN * 32];

    const int NC = gridDim.x, NR = gridDim.y;
    int g = blockIdx.y * NC + blockIdx.x;
    int per = NC * 8;
    int nfull = (NR >> 3) * per;
    int rowt, colt;
    if (g < nfull) {
        int grp = g / per, rem = g % per;
        rowt = grp * 8 + (rem & 7);
        colt = rem >> 3;
    } else {
        int rem = g - nfull;
        int tail = NR - (NR >> 3) * 8;
        rowt = (NR >> 3) * 8 + rem % tail;
        colt = rem / tail;
    }

    const int t = threadIdx.x;
    const int row0 = rowt * BM;
    const int col0 = colt * BN;

    const int wv   = t >> 6;
    const int lane = t & 63;
    const int quad = lane >> 4;
    const int l16  = lane & 15;
    const int wrow = (wv >> 1) * (BM / 2);
    const int wcol = (wv & 1) * WN;

    const int subrow = lane >> 2;                          // 0..15
    const int kchunk = (lane & 3) ^ (subrow & 3);          // swizzled chunk
    const int subkg  = kchunk * 8;

    f32x4 acc[MI][BF] = {};

    for (int k0 = 0; k0 < K; k0 += 64) {
        #pragma unroll
        for (int h = 0; h < 2; h++) {
            int kh = k0 + h * 32;
            #pragma unroll
            for (int p = 0; p < APASS; p++) {
                int rowA = (p * 4 + wv) * 16 + subrow;
                const __hip_bfloat16* gp = Ab + (size_t)(row0 + rowA) * lda + kh + subkg;
                __builtin_amdgcn_global_load_lds((gu32p)(const void*)gp,
                    (lu32p)(void*)&As[h][(p * 4 + wv) * 512], 16, 0, 0);
            }
            #pragma unroll
            for (int p = 0; p < BPASS; p++) {
                int rowB = (p * 4 + wv) * 16 + subrow;
                const __hip_bfloat16* gp = Bt + (size_t)(col0 + rowB) * ldb + kh + subkg;
                __builtin_amdgcn_global_load_lds((gu32p)(const void*)gp,
                    (lu32p)(void*)&Bs[h][(p * 4 + wv) * 512], 16, 0, 0);
            }
        }
        __syncthreads();

        #pragma unroll
        for (int h = 0; h < 2; h++) {
            bf16x8 af[MI], bfr[BF];
            #pragma unroll
            for (int i = 0; i < MI; i++) {
                int R = wrow + i * 16 + l16;
                af[i] = *(const bf16x8*)&As[h][R * 32 + ((quad ^ (R & 3)) * 8)];
            }
            #pragma unroll
            for (int j = 0; j < BF; j++) {
                int R = wcol + j * 16 + l16;
                bfr[j] = *(const bf16x8*)&Bs[h][R * 32 + ((quad ^ (R & 3)) * 8)];
            }
            #pragma unroll
            for (int i = 0; i < MI; i++)
                #pragma unroll
                for (int j = 0; j < BF; j++)
                    acc[i][j] = __builtin_amdgcn_mfma_f32_16x16x32_bf16(af[i], bfr[j], acc[i][j], 0, 0, 0);
        }
        if (k0 + 64 < K) __syncthreads();
    }

    #pragma unroll
    for (int i = 0; i < MI; i++) {
        #pragma unroll
        for (int j = 0; j < BF; j++) {
            int n = col0 + wcol + j * 16 + l16;
            bool second = (n >= splitN);
            float bv = bias ? bias[n] : 0.f;
            #pragma unroll
            for (int reg = 0; reg < 4; reg++) {
                int m = row0 + wrow + i * 16 + quad * 4 + reg;
                if (m >= M) continue;
                float v = acc[i][j][reg] + bv;
                if (do_relu && !second) v = fmaxf(v, 0.f);
                if (second)
                    ((__hip_bfloat16*)Cout2)[(size_t)m * ldc2 + (n - splitN)] = __float2bfloat16(v);
                else if (out_bf16)
                    ((__hip_bfloat16*)Cout)[(size_t)m * ldc + n] = __float2bfloat16(v);
                else
                    ((float*)Cout)[(size_t)m * ldc + n] = v;
            }
        }
    }

    // ---- fused CSR scatter (G1 only), epilogue: overlaps other blocks ----
    if (ei) {
        const int EPB = 410;                          // 1955*410 >= 800000
        int e0 = g * EPB;
        int e1 = e0 + EPB; if (e1 > NEDGES) e1 = NEDGES;
        int ea = e0 + t, eb = ea + 256;               // EPB <= 512: 2 slots
        bool va = ea < e1, vb = eb < e1;
        int ra = 0, ca = 0, rb = 0, cb = 0;
        if (va) { ra = ei[ea]; ca = ei[NEDGES + ea]; }
        if (vb) { rb = ei[eb]; cb = ei[NEDGES + eb]; }
        int pa_ = va ? atomicAdd(&woff[ca], 1) : 0;   // both atomics in flight
        int pb_ = vb ? atomicAdd(&woff[cb], 1) : 0;
        if (va) *(int2*)(csr_rc + 2 * (size_t)pa_) = make_int2(ra, ca);
        if (vb) *(int2*)(csr_rc + 2 * (size_t)pb_) = make_int2(rb, cb);
    }
}

// ---------------- fused 2-stage GEMM ---------------------------------------
// Stage 1: T[64,BN1] = relu(A[M,K1] @ B1t[BN1,K1]^T + bias1) held in LDS.
// Stage 2: Out[64,N2] = T @ B2t[N2,BN1]^T + bias2.  (see round-4 notes)
template<int BN1, int WN1, int N2, int SPLIT2, int OUT2F32>
__global__ __launch_bounds__(256) void gemm_fused(
    const __hip_bfloat16* __restrict__ Ab, int lda,
    const __hip_bfloat16* __restrict__ B1t, int ldb1,
    const float* __restrict__ bias1,
    const __hip_bfloat16* __restrict__ B2t,
    const float* __restrict__ bias2,
    void* __restrict__ Out1, int ldo1,
    void* __restrict__ Out2, int ldo2,
    int M, int K1)
{
    constexpr int BF1 = WN1 / 16;
    constexpr int BPASS1 = BN1 / 64;
    constexpr int K2H = BN1 / 32;        // stage-2 K chunks of 32
    constexpr int WN2 = N2 / 2;
    constexpr int BF2 = WN2 / 16;
    constexpr int P2 = N2 / 64;
    __shared__ __bf16 L1[4096 + BN1 * 64];   // [As(2x2048) | Bs1(2 x BN1*32)]
    __shared__ __bf16 Bs2[8192];             // K2H x N2*32 (= BN1*N2 = 8192 both cfgs)

    const int t = threadIdx.x;
    const int row0 = blockIdx.y * 64;
    const int wv   = t >> 6;
    const int lane = t & 63;
    const int quad = lane >> 4;
    const int l16  = lane & 15;
    const int wrow1 = (wv >> 1) * 32;
    const int wcol1 = (wv & 1) * WN1;
    const int subrow = lane >> 2;
    const int subkg  = ((lane & 3) ^ (subrow & 3)) * 8;

    // stage B2 once (drains with first K-loop barrier)
    #pragma unroll
    for (int hh = 0; hh < K2H; hh++)
        #pragma unroll
        for (int p = 0; p < P2; p++) {
            int rowB = (p * 4 + wv) * 16 + subrow;
            const __hip_bfloat16* gp = B2t + (size_t)rowB * BN1 + hh * 32 + subkg;
            __builtin_amdgcn_global_load_lds((gu32p)(const void*)gp,
                (lu32p)(void*)&Bs2[hh * (N2 * 32) + (p * 4 + wv) * 512], 16, 0, 0);
        }

    f32x4 acc1[2][BF1] = {};
    for (int k0 = 0; k0 < K1; k0 += 64) {
        #pragma unroll
        for (int h = 0; h < 2; h++) {
            int kh = k0 + h * 32;
            {
                int rowA = wv * 16 + subrow;
                const __hip_bfloat16* gp = Ab + (size_t)(row0 + rowA) * lda + kh + subkg;
                __builtin_amdgcn_global_load_lds((gu32p)(const void*)gp,
                    (lu32p)(void*)&L1[h * 2048 + wv * 512], 16, 0, 0);
            }
            #pragma unroll
            for (int p = 0; p < BPASS1; p++) {
                int rowB = (p * 4 + wv) * 16 + subrow;
                const __hip_bfloat16* gp = B1t + (size_t)rowB * ldb1 + kh + subkg;
                __builtin_amdgcn_global_load_lds((gu32p)(const void*)gp,
                    (lu32p)(void*)&L1[4096 + h * (BN1 * 32) + (p * 4 + wv) * 512], 16, 0, 0);
            }
        }
        __syncthreads();
        #pragma unroll
        for (int h = 0; h < 2; h++) {
            bf16x8 af[2], bfr[BF1];
            #pragma unroll
            for (int i = 0; i < 2; i++) {
                int R = wrow1 + i * 16 + l16;
                af[i] = *(const bf16x8*)&L1[h * 2048 + R * 32 + ((quad ^ (R & 3)) * 8)];
            }
            #pragma unroll
            for (int j = 0; j < BF1; j++) {
                int R = wcol1 + j * 16 + l16;
                bfr[j] = *(const bf16x8*)&L1[4096 + h * (BN1 * 32) + R * 32 + ((quad ^ (R & 3)) * 8)];
            }
            #pragma unroll
            for (int i = 0; i < 2; i++)
                #pragma unroll
                for (int j = 0; j < BF1; j++)
                    acc1[i][j] = __builtin_amdgcn_mfma_f32_16x16x32_bf16(af[i], bfr[j], acc1[i][j], 0, 0, 0);
        }
        __syncthreads();   // ALWAYS: T overlays As/Bs next (or next stage)
    }

    // T = relu(acc1 + bias1) -> bf16 into L1 (swizzled layout, overlay)
    #pragma unroll
    for (int i = 0; i < 2; i++)
        #pragma unroll
        for (int j = 0; j < BF1; j++) {
            int n1 = wcol1 + j * 16 + l16;
            float bv = bias1[n1];
            int h = n1 >> 5, kk = n1 & 31;
            int q = kk >> 3, pp = kk & 7;
            #pragma unroll
            for (int reg = 0; reg < 4; reg++) {
                int r = wrow1 + i * 16 + quad * 4 + reg;
                float v = fmaxf(acc1[i][j][reg] + bv, 0.f);
                __hip_bfloat16 hb = __float2bfloat16(v);
                unsigned short us; memcpy(&us, &hb, 2);
                *(unsigned short*)&L1[h * 2048 + r * 32 + ((q ^ (r & 3)) * 8) + pp] = us;
            }
        }
    __syncthreads();

    // stage 2
    const int wrow2 = (wv >> 1) * 32;
    const int wcol2 = (wv & 1) * WN2;
    f32x4 acc2[2][BF2] = {};
    #pragma unroll
    for (int hh = 0; hh < K2H; hh++) {
        bf16x8 af2[2], bf2[BF2];
        #pragma unroll
        for (int i = 0; i < 2; i++) {
            int R = wrow2 + i * 16 + l16;
            af2[i] = *(const bf16x8*)&L1[hh * 2048 + R * 32 + ((quad ^ (R & 3)) * 8)];
        }
        #pragma unroll
        for (int j = 0; j < BF2; j++) {
            int R = wcol2 + j * 16 + l16;
            bf2[j] = *(const bf16x8*)&Bs2[hh * (N2 * 32) + R * 32 + ((quad ^ (R & 3)) * 8)];
        }
        #pragma unroll
        for (int i = 0; i < 2; i++)
            #pragma unroll
            for (int j = 0; j < BF2; j++)
                acc2[i][j] = __builtin_amdgcn_mfma_f32_16x16x32_bf16(af2[i], bf2[j], acc2[i][j], 0, 0, 0);
    }

    #pragma unroll
    for (int i = 0; i < 2; i++)
        #pragma unroll
        for (int j = 0; j < BF2; j++) {
            int n2 = wcol2 + j * 16 + l16;
            float bv = bias2[n2];
            #pragma unroll
            for (int reg = 0; reg < 4; reg++) {
                int m = row0 + wrow2 + i * 16 + quad * 4 + reg;
                if (m >= M) continue;
                float v = acc2[i][j][reg] + bv;
                if (SPLIT2) {
                    if (n2 < 64)
                        ((__hip_bfloat16*)Out1)[(size_t)m * ldo1 + n2] = __float2bfloat16(v);
                    else
                        ((__hip_bfloat16*)Out2)[(size_t)m * ldo2 + (n2 - 64)] = __float2bfloat16(v);
                } else if (OUT2F32) {
                    ((float*)Out1)[(size_t)m * ldo1 + n2] = v;
                } else {
                    ((__hip_bfloat16*)Out1)[(size_t)m * ldo1 + n2] = __float2bfloat16(v);
                }
            }
        }
}

// ---------------- CSR build (count fused into prep; scatter fused into G1) -
// scan1 merges the 8 per-XCD count replicas, stores merged cnt, scans.
__global__ __launch_bounds__(256) void scan1_kernel(
    const int* __restrict__ cnt8, int* __restrict__ cnt,
    int* __restrict__ incl, int* __restrict__ bsum)
{
    __shared__ int s[256];
    int t = threadIdx.x;
    int i = blockIdx.x * 256 + t;
    int v = 0;
    if (i < NNODES) {
        #pragma unroll
        for (int x = 0; x < 8; x++) v += cnt8[x * NNODES + i];
        cnt[i] = v;
    }
    s[t] = v;
    __syncthreads();
    for (int off = 1; off < 256; off <<= 1) {
        int u = (t >= off) ? s[t - off] : 0;
        __syncthreads();
        s[t] += u;
        __syncthreads();
    }
    if (i < NNODES) incl[i] = s[t];
    if (t == 255) bsum[blockIdx.x] = s[255];
}

// scan3 with scan2 folded in (identical integer math to scan2+scan3 pair).
__global__ __launch_bounds__(256) void scan3_kernel(
    const int* __restrict__ cnt, const int* __restrict__ incl,
    const int* __restrict__ bsum, int* __restrict__ rowptr,
    int* __restrict__ woff, int nb)
{
    __shared__ int s[256];
    int t = threadIdx.x;
    int v = (t < nb) ? bsum[t] : 0;
    s[t] = v;
    __syncthreads();
    for (int off = 1; off < 256; off <<= 1) {
        int u = (t >= off) ? s[t - off] : 0;
        __syncthreads();
        s[t] += u;
        __syncthreads();
    }
    int off = s[blockIdx.x] - bsum[blockIdx.x];   // exclusive prefix of own block
    int i = blockIdx.x * 256 + t;
    if (i >= NNODES) return;
    int r = incl[i] - cnt[i] + off;
    rowptr[i] = r;
    woff[i] = r;
    if (i == NNODES - 1) rowptr[NNODES] = incl[i] + off;
}

// ---------------- edge weight: 8 lanes per edge; partial sums NO atomics ---
// Round-6 lesson: 50000 same-address double atomicAdds serialized (~600us);
// per-block partials (plain stores) + tiny reduce instead.
__global__ __launch_bounds__(256) void edge_ew_gather(
    const __hip_bfloat16* __restrict__ lg, const __hip_bfloat16* __restrict__ pe,
    const int* __restrict__ csr_rc,
    float* __restrict__ ew_csr, double* __restrict__ part)
{
    const int tid = threadIdx.x;
    const int sub = tid & 7;
    const int e = blockIdx.x * 32 + (tid >> 3);   // 25000*32 == 800000 exactly
    int2 rc = *(const int2*)(csr_rc + 2 * (size_t)e);
    bf16x8 a = *(const bf16x8*)(lg + (size_t)rc.x * CD + sub * 8);
    bf16x8 b = *(const bf16x8*)(pe + (size_t)rc.y * CD + sub * 8);
    float acc = 0.f;
    #pragma unroll
    for (int u = 0; u < 8; u++)
        acc += (float)a[u] * (float)b[u];
    acc += __shfl_xor(acc, 1);
    acc += __shfl_xor(acc, 2);
    acc += __shfl_xor(acc, 4);
    if (sub == 0) ew_csr[e] = acc;

    double s1 = (sub == 0) ? (double)acc : 0.0;
    double s2 = (sub == 0) ? (double)acc * (double)acc : 0.0;
    #pragma unroll
    for (int off = 8; off < 64; off <<= 1) {      // combine the 8 sub0 lanes/wave
        s1 += __shfl_xor(s1, off);
        s2 += __shfl_xor(s2, off);
    }
    __shared__ double sh1[4], sh2[4];
    if ((tid & 63) == 0) { sh1[tid >> 6] = s1; sh2[tid >> 6] = s2; }
    __syncthreads();
    if (tid == 0) {
        part[2 * blockIdx.x]     = sh1[0] + sh1[1] + sh1[2] + sh1[3];
        part[2 * blockIdx.x + 1] = sh2[0] + sh2[1] + sh2[2] + sh2[3];
    }
}

// reduce the 25000 partial pairs into S (64 total atomics -- no contention)
__global__ __launch_bounds__(256) void ew_reduce_kernel(
    const double* __restrict__ part, double* __restrict__ S)
{
    const int tid = threadIdx.x;
    double s1 = 0.0, s2 = 0.0;
    for (int i = blockIdx.x * 256 + tid; i < 25000; i += gridDim.x * 256) {
        s1 += part[2 * i];
        s2 += part[2 * i + 1];
    }
    __shared__ double sh1[256], sh2[256];
    sh1[tid] = s1; sh2[tid] = s2;
    __syncthreads();
    for (int s = 128; s > 0; s >>= 1) {
        if (tid < s) { sh1[tid] += sh1[tid + s]; sh2[tid] += sh2[tid + s]; }
        __syncthreads();
    }
    if (tid == 0) {
        atomicAdd(&S[0], sh1[0]);
        atomicAdd(&S[1], sh2[0]);
    }
}

// per node: normalize segment in place, deg = segment sum, dis = rsqrt(deg+1).
__global__ __launch_bounds__(256) void norm_deg_kernel(
    const int* __restrict__ rowptr, float* __restrict__ ew_csr,
    const double* __restrict__ S, float* __restrict__ dis)
{
    int n = blockIdx.x * 256 + threadIdx.x;
    if (n >= NNODES) return;
    const double Ed = (double)NEDGES;
    double meand = S[0] / Ed;
    double var = (S[1] - S[0] * S[0] / Ed) / (Ed - 1.0);
    float mean = (float)meand;
    float alpha = (float)sqrt(1e-4 / var);
    int s = rowptr[n], e = rowptr[n + 1];
    float sum = 0.f;
    for (int j = s; j < e; j++) {
        float w = (ew_csr[j] - mean) * alpha + 1.0f;
        ew_csr[j] = w;
        sum += w;
    }
    float d = sum + 1.0f;                       // self-loop weight 1
    dis[n] = (d > 0.f) ? rsqrtf(d) : 0.f;
}

// per node: ew[j] *= dis[row]*dis[n] IN PLACE (ew becomes final csr_w)
__global__ __launch_bounds__(256) void csrw_kernel(
    const int* __restrict__ rowptr, const int* __restrict__ csr_rc,
    float* __restrict__ ew_csr, const float* __restrict__ dis)
{
    int n = blockIdx.x * 256 + threadIdx.x;
    if (n >= NNODES) return;
    float dn = dis[n];
    int s = rowptr[n], e = rowptr[n + 1];
    for (int j = s; j < e; j++)
        ew_csr[j] = dis[csr_rc[2 * (size_t)j]] * ew_csr[j] * dn;
}

// ---------------- weighted aggregation, MLP-optimized ----------------------
__global__ __launch_bounds__(128) void agg_kernel(
    const unsigned* __restrict__ xw32, const float* __restrict__ dis,
    const int* __restrict__ rowptr, const int* __restrict__ csr_rc,
    const float* __restrict__ csr_w, const float* __restrict__ bias,
    __hip_bfloat16* __restrict__ out, int ldo)
{
    const int wv = threadIdx.x >> 6, lane = threadIdx.x & 63;
    const int n = blockIdx.x * 2 + wv;
    if (n >= NNODES) return;
    float dn = dis[n];
    unsigned v0 = xw32[(size_t)n * 64 + lane];
    float aL = dn * dn * __uint_as_float(v0 << 16);
    float aH = dn * dn * __uint_as_float(v0 & 0xffff0000u);
    int s = rowptr[n], e = rowptr[n + 1];
    int j = s;
    for (; j + 4 <= e; j += 4) {
        int r0 = csr_rc[2 * (size_t)(j)];
        int r1 = csr_rc[2 * (size_t)(j + 1)];
        int r2 = csr_rc[2 * (size_t)(j + 2)];
        int r3 = csr_rc[2 * (size_t)(j + 3)];
        float w0 = csr_w[j], w1 = csr_w[j + 1];
        float w2 = csr_w[j + 2], w3 = csr_w[j + 3];
        unsigned g0 = xw32[(size_t)r0 * 64 + lane];
        unsigned g1 = xw32[(size_t)r1 * 64 + lane];
        unsigned g2 = xw32[(size_t)r2 * 64 + lane];
        unsigned g3 = xw32[(size_t)r3 * 64 + lane];
        aL = fmaf(w0, __uint_as_float(g0 << 16), aL);
        aH = fmaf(w0, __uint_as_float(g0 & 0xffff0000u), aH);
        aL = fmaf(w1, __uint_as_float(g1 << 16), aL);
        aH = fmaf(w1, __uint_as_float(g1 & 0xffff0000u), aH);
        aL = fmaf(w2, __uint_as_float(g2 << 16), aL);
        aH = fmaf(w2, __uint_as_float(g2 & 0xffff0000u), aH);
        aL = fmaf(w3, __uint_as_float(g3 << 16), aL);
        aH = fmaf(w3, __uint_as_float(g3 & 0xffff0000u), aH);
    }
    for (; j < e; j++) {
        int r = csr_rc[2 * (size_t)j];
        float w = csr_w[j];
        unsigned g = xw32[(size_t)r * 64 + lane];
        aL = fmaf(w, __uint_as_float(g << 16), aL);
        aH = fmaf(w, __uint_as_float(g & 0xffff0000u), aH);
    }
    float2 b = *(const float2*)(bias + 2 * lane);
    aL = fmaxf(aL + b.x, 0.f);
    aH = fmaxf(aH + b.y, 0.f);
    __hip_bfloat16 bl = __float2bfloat16(aL), bh = __float2bfloat16(aH);
    unsigned short ul, uh;
    memcpy(&ul, &bl, 2); memcpy(&uh, &bh, 2);
    unsigned o = (unsigned)ul | ((unsigned)uh << 16);
    *(unsigned*)(out + (size_t)n * ldo + 2 * lane) = o;
}

// ---------------- launch --------------------------------------------------
extern "C" void kernel_launch(void* const* d_in, const int* in_sizes, int n_in,
                              void* d_out, int out_size, void* d_ws, size_t ws_size,
                              hipStream_t stream)
{
    const float* x   = (const float*)d_in[0];
    const int*   ei  = (const int*)d_in[1];
    const float* Wp1 = (const float*)d_in[2];
    const float* bp1 = (const float*)d_in[3];
    const float* Wp2 = (const float*)d_in[4];
    const float* bp2 = (const float*)d_in[5];
    const float* Wp3 = (const float*)d_in[6];
    const float* bp3 = (const float*)d_in[7];
    const float* P0  = (const float*)d_in[8];
    const float* Wg0 = (const float*)d_in[9];
    const float* bg0 = (const float*)d_in[10];
    const float* Wg1 = (const float*)d_in[11];
    const float* bg1 = (const float*)d_in[12];
    // d_in[13], d_in[14] = Wg2/bg2: dead in reference
    const float* Wl1 = (const float*)d_in[15];
    const float* bl1 = (const float*)d_in[16];
    const float* Wl2 = (const float*)d_in[17];
    const float* bl2 = (const float*)d_in[18];
    float* out = (float*)d_out;

    char* wsb = (char*)d_ws;
    __hip_bfloat16* xj     = (__hip_bfloat16*)(wsb + XJ_B);
    __hip_bfloat16* xb16   = (__hip_bfloat16*)(wsb + XJ_B);  // x bf16 overlay (early)
    double*         part   = (double*)(wsb + HID_B);         // ew partials (post-G1)
    __hip_bfloat16* h1     = (__hip_bfloat16*)(wsb + H1_B);
    __hip_bfloat16* xw     = (__hip_bfloat16*)(wsb + XW_B);
    int*            cnt8   = (int*)(wsb + CNT8_B);           // per-XCD degree counters
    __hip_bfloat16* lg     = (__hip_bfloat16*)(wsb + LG_B);
    __hip_bfloat16* pe     = (__hip_bfloat16*)(wsb + PE_B);
    int*            csr_rc = (int*)(wsb + CSRRC_B);          // int2 (row,col) pairs
    float*          ew_csr = (float*)(wsb + EWC_B);          // ew -> final csr_w in place
    int*            cnt    = (int*)(wsb + CNT_B);
    double*         S      = (double*)(wsb + S_B);
    int*            rowptr = (int*)(wsb + RP_B);
    int*            woff   = (int*)(wsb + WOFF_B);
    int*            incl   = (int*)(wsb + INCL_B);
    int*            bsum   = (int*)(wsb + BSUM_B);
    float*          dis    = (float*)(wsb + DIS_B);

    __hip_bfloat16* Wp1t = (__hip_bfloat16*)(wsb + WT_B + WP1T_O);
    __hip_bfloat16* Wg0t = (__hip_bfloat16*)(wsb + WT_B + WG0T_O);
    __hip_bfloat16* Wp2t = (__hip_bfloat16*)(wsb + WT_B + WP2T_O);
    __hip_bfloat16* Wp3t = (__hip_bfloat16*)(wsb + WT_B + WP3T_O);
    __hip_bfloat16* W2t  = (__hip_bfloat16*)(wsb + WT_B + W2T_O);
    __hip_bfloat16* Wg1t = (__hip_bfloat16*)(wsb + WT_B + WG1T_O);
    __hip_bfloat16* Wl1t = (__hip_bfloat16*)(wsb + WT_B + WL1T_O);
    __hip_bfloat16* Wl2t = (__hip_bfloat16*)(wsb + WT_B + WL2T_O);
    float*          bias_g1 = (float*)(wsb + WT_B + BG1_O);
    float*          bias_g3 = (float*)(wsb + WT_B + BG3_O);

    const int NB = (NNODES + 255) / 256;            // 196
    const int MT  = (NNODES + 127) / 128;           // 391 row tiles (BM=128)
    const int MT64 = (NNODES + 63) / 64;            // 782 row tiles (BM=64)
    const int BIGN = 1 << 30;

    hipMemsetAsync(wsb + CNT8_B, 0, 8 * NNODES * sizeof(int), stream);
    hipMemsetAsync(wsb + S_B, 0, 16, stream);

    // --- fused prep: x cast (+edge counts interleaved) + transposes + P0 ---
    PrepArgs pa;
    pa.x = x; pa.xb = xb16;
    pa.w[0] = { Wp1, Wp1t, 512, 512 };
    pa.w[1] = { Wg0, Wg0t, 512, 128 };
    pa.w[2] = { Wp2, Wp2t, 512,  64 };
    pa.w[3] = { Wp3, Wp3t,  64,  64 };
    pa.w[4] = { Wg1, Wg1t, 128, 128 };
    pa.w[5] = { Wl1, Wl1t, 256, 128 };
    pa.w[6] = { Wl2, Wl2t, 128,  64 };
    // 64x64 tiles per matrix: 64,16,8,1,4,8,2 (cumulative below)
    pa.bo[0] = 0;  pa.bo[1] = 64; pa.bo[2] = 80; pa.bo[3] = 88;
    pa.bo[4] = 89; pa.bo[5] = 93; pa.bo[6] = 101; pa.bo[7] = 103;
    pa.Wp3 = Wp3; pa.bp3 = bp3; pa.P0 = P0; pa.bp1 = bp1;
    pa.W2t = W2t; pa.bias_g1 = bias_g1; pa.bias_g3 = bias_g3;
    pa.ei = ei; pa.cnt8 = cnt8;
    prep_all<<<PREP_BLKS, 256, 0, stream>>>(pa);

    // --- CSR scans (scatter is fused into G1's epilogue) ---
    scan1_kernel<<<NB, 256, 0, stream>>>(cnt8, cnt, incl, bsum);
    scan3_kernel<<<NB, 256, 0, stream>>>(cnt, incl, bsum, rowptr, woff, NB);

    // --- fused G1: [h1 | xw] = x @ [Wp1 | Wg0]^T  + CSR scatter (epilogue) ---
    gemm_mfma<128, 128, 64><<<dim3(5, MT), 256, 0, stream>>>(
        xb16, 512, Wp1t, 512, bias_g1, h1, 512, xw, 128, 512, NNODES, 512, 1, 1,
        ei, woff, csr_rc);

    // --- fused G2+G3: h2 = relu(h1@Wp2+bp2) in LDS; [lg|pe] = h2@[Wp3|W2]^T ---
    gemm_fused<64, 32, 128, 1, 0><<<dim3(1, MT64), 256, 0, stream>>>(
        h1, 512, Wp2t, 512, bp2, Wp3t, bias_g3, lg, 64, pe, 64, NNODES, 512);

    // --- per-edge weights (partial sums, no atomics) + tiny reduce ---
    edge_ew_gather<<<NEDGES / 32, 256, 0, stream>>>(lg, pe, csr_rc, ew_csr, part);
    ew_reduce_kernel<<<32, 256, 0, stream>>>(part, S);
    norm_deg_kernel<<<NB, 256, 0, stream>>>(rowptr, ew_csr, S, dis);
    csrw_kernel<<<NB, 256, 0, stream>>>(rowptr, csr_rc, ew_csr, dis);

    // --- GCN layer 0 aggregation (xw from fused G1) ---
    agg_kernel<<<25000, 128, 0, stream>>>((const unsigned*)xw, dis, rowptr, csr_rc, ew_csr, bg0, xj, 2 * HD);

    // --- GCN layer 1 ---
    gemm_mfma<64, 64, 32><<<dim3(2, MT64), 256, 0, stream>>>(
        xj, 2 * HD, Wg1t, 128, nullptr, xw, 128, nullptr, 0, BIGN, NNODES, 128, 0, 1,
        nullptr, nullptr, nullptr);
    agg_kernel<<<25000, 128, 0, stream>>>((const unsigned*)xw, dis, rowptr, csr_rc, ew_csr, bg1, xj + HD, 2 * HD);

    // --- fused JK head: hid = relu(xj@Wl1+bl1) in LDS; out = hid@Wl2+bl2 ---
    gemm_fused<128, 64, 64, 0, 1><<<dim3(1, MT64), 256, 0, stream>>>(
        xj, 2 * HD, Wl1t, 256, bl1, Wl2t, bl2, out, 64, nullptr, 0, NNODES, 256);
}